// Round 5
// baseline (3800.460 us; speedup 1.0000x reference)
//
#include <hip/hip_runtime.h>

typedef __attribute__((ext_vector_type(4))) float f32x4;

// ---------------------------------------------------------------------------
// Simple f32 GEMM: C[m][n] = sum_k A[m][k]*W[k][n] + bias[n]
// A: f32 [M][lda] ; W: f32 [K][N] natural layout ; C: f32 [M][N]
// grid (N/256, M/16), block 256. Requires M%16==0, N%256==0, K%64==0.
// ---------------------------------------------------------------------------
__global__ __launch_bounds__(256) void gemm_simple(
    const float* __restrict__ A, const float* __restrict__ W,
    const float* __restrict__ bias, float* __restrict__ C,
    int M, int N, int K, int lda)
{
    __shared__ float As[16][64];
    const int tid = threadIdx.x;
    const int n = blockIdx.x * 256 + tid;
    const int m0 = blockIdx.y * 16;

    float acc[16];
#pragma unroll
    for (int m = 0; m < 16; m++) acc[m] = 0.f;

    for (int k0 = 0; k0 < K; k0 += 64) {
        __syncthreads();
#pragma unroll
        for (int i = 0; i < 4; i++) {
            int idx = i * 256 + tid;          // 0..1023
            int r = idx >> 6, c = idx & 63;
            As[r][c] = A[(long)(m0 + r) * lda + k0 + c];
        }
        __syncthreads();
#pragma unroll 4
        for (int kk = 0; kk < 64; kk++) {
            float w = W[(long)(k0 + kk) * N + n];
#pragma unroll
            for (int m = 0; m < 16; m++)
                acc[m] = fmaf(As[m][kk], w, acc[m]);
        }
    }

    const float b = bias ? bias[n] : 0.f;
#pragma unroll
    for (int m = 0; m < 16; m++) {
        long off = (long)(m0 + m) * N + n;
        C[off] = acc[m] + b;
    }
}

// ---------------------------------------------------------------------------
// attention scores + softmax for one (b,q) row.
// grid 4032, block 128. P: f32 [4032][128] (cols >=126 zero).
// ---------------------------------------------------------------------------
__global__ __launch_bounds__(128) void attn_sm(
    const float* __restrict__ Q, const float* __restrict__ Km,
    float* __restrict__ P)
{
    const int blk = blockIdx.x;          // 0..4031 = b*126 + q
    const int b = blk / 126, q = blk - b * 126;
    const int tid = threadIdx.x;
    __shared__ float qs[512];
    __shared__ float red[4];

    *(f32x4*)(qs + tid * 4) = *(const f32x4*)(Q + (long)blk * 512 + tid * 4);
    __syncthreads();

    const int j = tid;
    const bool ok = (j < 126) && ((j < 50) || (j <= q));
    float s = -3.0e38f;
    if (ok) {
        const float* kr = Km + (long)(b * 126 + j) * 512;
        float acc = 0.f;
        for (int d = 0; d < 512; d += 4) {
            f32x4 kv = *(const f32x4*)(kr + d);
            acc += qs[d] * kv[0] + qs[d + 1] * kv[1]
                 + qs[d + 2] * kv[2] + qs[d + 3] * kv[3];
        }
        s = acc * 0.044194173824159216f;   // 1/sqrt(512)
    }
    float m = s;
#pragma unroll
    for (int o = 32; o >= 1; o >>= 1) m = fmaxf(m, __shfl_xor(m, o));
    if ((tid & 63) == 0) red[tid >> 6] = m;
    __syncthreads();
    m = fmaxf(red[0], red[1]);

    float e = ok ? expf(s - m) : 0.f;
    float t = e;
#pragma unroll
    for (int o = 32; o >= 1; o >>= 1) t += __shfl_xor(t, o);
    if ((tid & 63) == 0) red[2 + (tid >> 6)] = t;
    __syncthreads();
    float sum = red[2] + red[3];

    P[(long)blk * 128 + tid] = e / sum;
}

// ---------------------------------------------------------------------------
// PV: Out[blk][d] = sum_j P[blk][j] * V[b*126+j][d]   (V already has wv_b)
// grid 4032, block 128 (each thread 4 d's).
// ---------------------------------------------------------------------------
__global__ __launch_bounds__(128) void attn_pv(
    const float* __restrict__ P, const float* __restrict__ V,
    float* __restrict__ Out)
{
    const int blk = blockIdx.x;
    const int b = blk / 126;
    const int tid = threadIdx.x;
    __shared__ float ps[128];
    ps[tid] = P[(long)blk * 128 + tid];
    __syncthreads();

    const int d = tid * 4;
    f32x4 acc = (f32x4)0.f;
    const float* vbase = V + (long)(b * 126) * 512 + d;
    for (int j = 0; j < 126; j++) {
        float p = ps[j];
        f32x4 vv = *(const f32x4*)(vbase + (long)j * 512);
        acc += p * vv;
    }
    *(f32x4*)(Out + (long)blk * 512 + d) = acc;
}

// ---------------------------------------------------------------------------
// x = LN(concat(img_out, tok_emb[cap]+pos)), grid 4032 x 64
// ---------------------------------------------------------------------------
__global__ __launch_bounds__(64) void build_x(
    const float* __restrict__ imgout, const int* __restrict__ cap,
    const float* __restrict__ tok, const float* __restrict__ pos,
    const float* __restrict__ g, const float* __restrict__ bb,
    float* __restrict__ x)
{
    const int r = blockIdx.x;            // 0..4031
    const int lane = threadIdx.x;
    const int c0 = lane << 3;
    const long base = ((long)r << 9) + c0;
    const int b = r / 126, s = r - b * 126;

    float v[8];
    if (s < 50) {
        const float* src = imgout + ((long)(b * 50 + s) << 9) + c0;
        f32x4 a0 = *(const f32x4*)src, a1 = *(const f32x4*)(src + 4);
#pragma unroll
        for (int i = 0; i < 4; i++) { v[i] = a0[i]; v[4 + i] = a1[i]; }
    } else {
        const int t = s - 50;
        const int id = cap[b * 76 + t];
        const float* s1 = tok + ((long)id << 9) + c0;
        const float* s2 = pos + ((long)t << 9) + c0;
        f32x4 a0 = *(const f32x4*)s1, a1 = *(const f32x4*)(s1 + 4);
        f32x4 b0 = *(const f32x4*)s2, b1 = *(const f32x4*)(s2 + 4);
#pragma unroll
        for (int i = 0; i < 4; i++) { v[i] = a0[i] + b0[i]; v[4 + i] = a1[i] + b1[i]; }
    }
    float sum = 0.f, sq = 0.f;
#pragma unroll
    for (int i = 0; i < 8; i++) { sum += v[i]; sq += v[i] * v[i]; }
#pragma unroll
    for (int o = 32; o >= 1; o >>= 1) { sum += __shfl_xor(sum, o); sq += __shfl_xor(sq, o); }
    const float mean = sum * (1.f / 512.f);
    const float var = sq * (1.f / 512.f) - mean * mean;
    const float inv = rsqrtf(var + 1e-5f);
#pragma unroll
    for (int i = 0; i < 8; i++)
        x[base + i] = (v[i] - mean) * inv * g[c0 + i] + bb[c0 + i];
}

// ---------------------------------------------------------------------------
// x = LN(a + x), grid 4032 x 64
// ---------------------------------------------------------------------------
__global__ __launch_bounds__(64) void resln(
    const float* __restrict__ a, const float* __restrict__ g,
    const float* __restrict__ bb, float* __restrict__ x)
{
    const int r = blockIdx.x;
    const int lane = threadIdx.x;
    const int c0 = lane << 3;
    const long base = ((long)r << 9) + c0;

    f32x4 a0 = *(const f32x4*)(a + base), a1 = *(const f32x4*)(a + base + 4);
    f32x4 x0 = *(const f32x4*)(x + base), x1 = *(const f32x4*)(x + base + 4);
    float v[8];
#pragma unroll
    for (int i = 0; i < 4; i++) { v[i] = a0[i] + x0[i]; v[4 + i] = a1[i] + x1[i]; }
    float sum = 0.f, sq = 0.f;
#pragma unroll
    for (int i = 0; i < 8; i++) { sum += v[i]; sq += v[i] * v[i]; }
#pragma unroll
    for (int o = 32; o >= 1; o >>= 1) { sum += __shfl_xor(sum, o); sq += __shfl_xor(sq, o); }
    const float mean = sum * (1.f / 512.f);
    const float var = sq * (1.f / 512.f) - mean * mean;
    const float inv = rsqrtf(var + 1e-5f);
#pragma unroll
    for (int i = 0; i < 8; i++)
        x[base + i] = (v[i] - mean) * inv * g[c0 + i] + bb[c0 + i];
}

// ---------------------------------------------------------------------------
// gather text rows: At[b*76+t] = x[b*126+50+t], f32
// ---------------------------------------------------------------------------
__global__ __launch_bounds__(256) void gather_txt(
    const float* __restrict__ x, float* __restrict__ At)
{
    int idx = blockIdx.x * 256 + threadIdx.x;
    if (idx >= 2432 * 512) return;
    int r = idx >> 9, c = idx & 511;
    int b = r / 76, t = r - b * 76;
    At[idx] = x[((long)(b * 126 + 50 + t) << 9) + c];
}

// ---------------------------------------------------------------------------
extern "C" void kernel_launch(void* const* d_in, const int* in_sizes, int n_in,
                              void* d_out, int out_size, void* d_ws, size_t ws_size,
                              hipStream_t stream)
{
    const float* img   = (const float*)d_in[0];   // [32,50,768]
    const int*   cap   = (const int*)  d_in[1];   // [32,76]
    const float* tok   = (const float*)d_in[2];   // [49408,512]
    const float* pos   = (const float*)d_in[3];   // [76,512]
    const float* ff0_w = (const float*)d_in[4];   // [768,512]
    const float* ff0_b = (const float*)d_in[5];
    const float* wq    = (const float*)d_in[6];
    const float* wq_b  = (const float*)d_in[7];
    const float* wk    = (const float*)d_in[8];
    const float* wk_b  = (const float*)d_in[9];
    const float* wv    = (const float*)d_in[10];
    const float* wv_b  = (const float*)d_in[11];
    const float* ln_g  = (const float*)d_in[12];
    const float* ln_b  = (const float*)d_in[13];
    const float* ff1_w = (const float*)d_in[14];
    const float* ff1_b = (const float*)d_in[15];
    const float* ff2_w = (const float*)d_in[16];  // [512,49408]
    const float* ff2_b = (const float*)d_in[17];

    char* ws = (char*)d_ws;
    size_t o = 0;
    auto alloc = [&](size_t bytes) { size_t r = o; o += (bytes + 255) & ~(size_t)255; return r; };

    float* x    = (float*)(ws + alloc(4032ull * 512 * 4));  // 8.26 MB
    float* tmpf = (float*)(ws + alloc(4032ull * 512 * 4));
    float* qbuf = (float*)(ws + alloc(4032ull * 512 * 4));
    float* kbuf = (float*)(ws + alloc(4032ull * 512 * 4));
    float* vbuf = (float*)(ws + alloc(4032ull * 512 * 4));
    float* P    = (float*)(ws + alloc(4032ull * 128 * 4));  // 2.06 MB
    float* Atxt = (float*)(ws + alloc(2432ull * 512 * 4));  // 4.98 MB
    // total ~48.3 MB

    // ff0: imgout = img @ ff0_w + ff0_b  -> tmpf [1600][512]
    gemm_simple<<<dim3(2, 100), 256, 0, stream>>>(
        img, ff0_w, ff0_b, tmpf, 1600, 512, 768, 768);

    build_x<<<4032, 64, 0, stream>>>(tmpf, cap, tok, pos, ln_g, ln_b, x);

    for (int l = 0; l < 2; l++) {
        gemm_simple<<<dim3(2, 252), 256, 0, stream>>>(
            x, wq, wq_b, qbuf, 4032, 512, 512, 512);
        gemm_simple<<<dim3(2, 252), 256, 0, stream>>>(
            x, wk, wk_b, kbuf, 4032, 512, 512, 512);
        gemm_simple<<<dim3(2, 252), 256, 0, stream>>>(
            x, wv, wv_b, vbuf, 4032, 512, 512, 512);
        attn_sm<<<4032, 128, 0, stream>>>(qbuf, kbuf, P);
        attn_pv<<<4032, 128, 0, stream>>>(P, vbuf, tmpf);
        resln<<<4032, 64, 0, stream>>>(tmpf, ln_g, ln_b, x);
        gemm_simple<<<dim3(2, 252), 256, 0, stream>>>(
            x, ff1_w, ff1_b, tmpf, 4032, 512, 512, 512);
        resln<<<4032, 64, 0, stream>>>(tmpf, ln_g, ln_b, x);
    }

    gather_txt<<<(2432 * 512 + 255) / 256, 256, 0, stream>>>(x, Atxt);

    // logits: d_out (f32) = Atxt @ ff2_w + ff2_b
    gemm_simple<<<dim3(193, 152), 256, 0, stream>>>(
        Atxt, ff2_w, ff2_b, (float*)d_out, 2432, 49408, 512, 512);
}

// Round 6
// 618.431 us; speedup vs baseline: 6.1453x; 6.1453x over previous
//
#include <hip/hip_runtime.h>

typedef unsigned short ushort_t;
typedef __attribute__((ext_vector_type(8))) short short8;
typedef __attribute__((ext_vector_type(4))) float f32x4;
typedef __attribute__((ext_vector_type(4))) unsigned short bf4;
typedef __attribute__((ext_vector_type(8))) unsigned short bf8v;

__device__ __forceinline__ ushort_t f2bf(float f) {
    union { float f; unsigned u; } v; v.f = f;
    unsigned r = v.u + 0x7FFFu + ((v.u >> 16) & 1u);
    return (ushort_t)(r >> 16);
}

#define LDT 72  // padded LDS row stride in ushorts (144 B, 16B-aligned)

// ---------------------------------------------------------------------------
// Batched bf16 GEMM: C[m][n] = scale * sum_k A[m][k]*B'[n][k] + bias[n]
// A: bf16 [M][lda] rows. B operand:
//   BSRC=0: B is bf16 [N][ldb] rows (W^T layout), B'[n][k]=B[n][k]
//   BSRC=1: B is f32  [K][ldb]  (natural W),      B'[n][k]=B[k][n0+n]
// tile 128x128, BK=64, 4 waves (2x2), 16x16x32 MFMA, reg->LDS staging.
// (Validated end-to-end: rounds 1/3 produced logits bit-identical (bf16) to
//  the f32 reference pipeline of round 4/5.)
// ---------------------------------------------------------------------------
template <int BSRC>
__global__ __launch_bounds__(256) void gemm_bf16(
    const ushort_t* __restrict__ A, const void* __restrict__ Bv,
    float* __restrict__ C, ushort_t* __restrict__ Cb,
    const float* __restrict__ bias,
    int K, int lda, int ldb, int ldc,
    long sA, long sB, long sC,
    int validM, float scale)
{
    __shared__ __attribute__((aligned(16))) ushort_t As[128 * LDT];
    __shared__ __attribute__((aligned(16))) ushort_t Bs[128 * LDT];

    const int tid = threadIdx.x;
    const int lane = tid & 63;
    const int wave = tid >> 6;
    const int wr = wave >> 1, wc = wave & 1;
    const int tN = blockIdx.x, tM = blockIdx.y, bz = blockIdx.z;
    const int n0 = tN * 128;

    const ushort_t* Abase = A + (long)bz * sA + (long)tM * 128 * lda;
    const ushort_t* Bb = (BSRC == 0)
        ? (const ushort_t*)Bv + (long)bz * sB + (long)n0 * ldb : nullptr;
    const float* Bf = (BSRC == 1)
        ? (const float*)Bv + (long)bz * sB : nullptr;

    f32x4 acc[4][4];
#pragma unroll
    for (int m = 0; m < 4; m++)
#pragma unroll
        for (int n = 0; n < 4; n++) acc[m][n] = (f32x4)0.f;

    for (int ks = 0; ks < K; ks += 64) {
        // ---- global loads into registers ----
        short8 ar[4];
#pragma unroll
        for (int i = 0; i < 4; i++) {
            int ch = wave * 256 + i * 64 + lane;   // 16B-chunk id in [0,1024)
            int row = ch >> 3, c16 = ch & 7;
            ar[i] = *(const short8*)(Abase + (long)row * lda + ks + (c16 << 3));
        }
        short8 br[4];
        bf4 pk[8];
        if (BSRC == 0) {
#pragma unroll
            for (int i = 0; i < 4; i++) {
                int ch = wave * 256 + i * 64 + lane;
                int row = ch >> 3, c16 = ch & 7;
                br[i] = *(const short8*)(Bb + (long)row * ldb + ks + (c16 << 3));
            }
        } else {
#pragma unroll
            for (int q = 0; q < 8; q++) {
                int qid = q * 256 + tid;           // [0,2048)
                int n = qid & 127, kq = qid >> 7;  // kq in [0,16)
                const float* wp = Bf + (long)(ks + kq * 4) * ldb + n0 + n;
                bf4 p;
                p[0] = f2bf(wp[0]);
                p[1] = f2bf(wp[ldb]);
                p[2] = f2bf(wp[2 * (long)ldb]);
                p[3] = f2bf(wp[3 * (long)ldb]);
                pk[q] = p;
            }
        }

        if (ks) __syncthreads();   // previous tile's readers done

        // ---- LDS writes ----
#pragma unroll
        for (int i = 0; i < 4; i++) {
            int ch = wave * 256 + i * 64 + lane;
            int row = ch >> 3, c16 = ch & 7;
            *(short8*)(As + row * LDT + (c16 << 3)) = ar[i];
        }
        if (BSRC == 0) {
#pragma unroll
            for (int i = 0; i < 4; i++) {
                int ch = wave * 256 + i * 64 + lane;
                int row = ch >> 3, c16 = ch & 7;
                *(short8*)(Bs + row * LDT + (c16 << 3)) = br[i];
            }
        } else {
#pragma unroll
            for (int q = 0; q < 8; q++) {
                int qid = q * 256 + tid;
                int n = qid & 127, kq = qid >> 7;
                *(bf4*)(Bs + n * LDT + (kq << 2)) = pk[q];
            }
        }
        __syncthreads();

        // ---- MFMA ----
#pragma unroll
        for (int ksub = 0; ksub < 2; ksub++) {
            const int kk = ksub * 32 + ((lane >> 4) << 3);
            short8 af[4], bfr[4];
#pragma unroll
            for (int m = 0; m < 4; m++)
                af[m] = *(const short8*)(As + ((wr << 6) + m * 16 + (lane & 15)) * LDT + kk);
#pragma unroll
            for (int n = 0; n < 4; n++)
                bfr[n] = *(const short8*)(Bs + ((wc << 6) + n * 16 + (lane & 15)) * LDT + kk);
#pragma unroll
            for (int m = 0; m < 4; m++)
#pragma unroll
                for (int n = 0; n < 4; n++)
                    acc[m][n] = __builtin_amdgcn_mfma_f32_16x16x32_bf16(
                        af[m], bfr[n], acc[m][n], 0, 0, 0);
        }
        if (ks + 64 < K) __syncthreads();
    }

    const int rb = (wr << 6) + ((lane >> 4) << 2);
    const int cb = (wc << 6) + (lane & 15);
#pragma unroll
    for (int m = 0; m < 4; m++) {
#pragma unroll
        for (int i = 0; i < 4; i++) {
            int r = tM * 128 + rb + m * 16 + i;
            if (r >= validM) continue;
#pragma unroll
            for (int n = 0; n < 4; n++) {
                int cg = n0 + cb + n * 16;
                float v = acc[m][n][i] * scale + (bias ? bias[cg] : 0.f);
                long off = (long)bz * sC + (long)r * ldc + cg;
                if (C) C[off] = v;
                if (Cb) Cb[off] = f2bf(v);
            }
        }
    }
}

// ---------------------------------------------------------------------------
// transpose f32 [R][C] -> bf16 [C][R]
// ---------------------------------------------------------------------------
__global__ __launch_bounds__(256) void transpose_bf(
    const float* __restrict__ in, ushort_t* __restrict__ out, int R, int C)
{
    __shared__ float t[32][33];
    int c0 = blockIdx.x << 5, r0 = blockIdx.y << 5;
    int tx = threadIdx.x, ty = threadIdx.y;
#pragma unroll
    for (int i = 0; i < 4; i++)
        t[ty + i * 8][tx] = in[(long)(r0 + ty + i * 8) * C + c0 + tx];
    __syncthreads();
#pragma unroll
    for (int i = 0; i < 4; i++)
        out[(long)(c0 + ty + i * 8) * R + r0 + tx] = f2bf(t[tx][ty + i * 8]);
}

// f32 [validR][C] -> bf16 [Rpad][C] with zero pad
__global__ __launch_bounds__(256) void conv_pad(
    const float* __restrict__ in, ushort_t* __restrict__ out,
    int validR, int C, int total)
{
    int idx = blockIdx.x * 256 + threadIdx.x;
    if (idx >= total) return;
    int r = idx / C;
    float v = 0.f;
    if (r < validR) v = in[idx];
    out[idx] = f2bf(v);
}

// gather final-LN bf16 rows for txt positions -> Atxt [2560][512] (pad zero)
__global__ __launch_bounds__(256) void gather_txt(
    const ushort_t* __restrict__ xb, ushort_t* __restrict__ At)
{
    int idx = blockIdx.x * 256 + threadIdx.x;
    if (idx >= 2560 * 512) return;
    int r = idx >> 9, c = idx & 511;
    if (r < 2432) {
        int b = r / 76, t = r - b * 76;
        At[idx] = xb[((long)(b * 126 + 50 + t) << 9) + c];
    } else {
        At[idx] = 0;
    }
}

// build x = LN(concat(img_out, tok_emb[cap]+pos)) ; rows >= 4032 zeroed
__global__ __launch_bounds__(64) void build_x(
    const float* __restrict__ imgout, const int* __restrict__ cap,
    const float* __restrict__ tok, const float* __restrict__ pos,
    const float* __restrict__ g, const float* __restrict__ bb,
    float* __restrict__ x, ushort_t* __restrict__ xb)
{
    int r = blockIdx.x, lane = threadIdx.x;
    int c0 = lane << 3;
    long base = ((long)r << 9) + c0;
    if (r >= 4032) {
        *(f32x4*)(x + base) = (f32x4)0.f;
        *(f32x4*)(x + base + 4) = (f32x4)0.f;
        *(bf8v*)(xb + base) = (bf8v)0;
        return;
    }
    int b = r / 126, s = r - b * 126;
    float v[8];
    if (s < 50) {
        const float* src = imgout + ((long)(b * 50 + s) << 9) + c0;
        f32x4 a0 = *(const f32x4*)src, a1 = *(const f32x4*)(src + 4);
#pragma unroll
        for (int i = 0; i < 4; i++) { v[i] = a0[i]; v[4 + i] = a1[i]; }
    } else {
        int t = s - 50;
        int id = cap[b * 76 + t];
        const float* s1 = tok + ((long)id << 9) + c0;
        const float* s2 = pos + ((long)t << 9) + c0;
        f32x4 a0 = *(const f32x4*)s1, a1 = *(const f32x4*)(s1 + 4);
        f32x4 b0 = *(const f32x4*)s2, b1 = *(const f32x4*)(s2 + 4);
#pragma unroll
        for (int i = 0; i < 4; i++) { v[i] = a0[i] + b0[i]; v[4 + i] = a1[i] + b1[i]; }
    }
    float sum = 0.f, sq = 0.f;
#pragma unroll
    for (int i = 0; i < 8; i++) { sum += v[i]; sq += v[i] * v[i]; }
#pragma unroll
    for (int o = 32; o >= 1; o >>= 1) { sum += __shfl_xor(sum, o); sq += __shfl_xor(sq, o); }
    float mean = sum * (1.f / 512.f);
    float var = sq * (1.f / 512.f) - mean * mean;
    float inv = rsqrtf(var + 1e-5f);
    bf8v ob;
#pragma unroll
    for (int i = 0; i < 8; i++) {
        float y = (v[i] - mean) * inv * g[c0 + i] + bb[c0 + i];
        x[base + i] = y;
        ob[i] = f2bf(y);
    }
    *(bf8v*)(xb + base) = ob;
}

// x = LN(a + x) ; rows >= 4032 zeroed
__global__ __launch_bounds__(64) void resln(
    const float* __restrict__ a, const float* __restrict__ g,
    const float* __restrict__ bb, float* __restrict__ x, ushort_t* __restrict__ xb)
{
    int r = blockIdx.x, lane = threadIdx.x;
    int c0 = lane << 3;
    long base = ((long)r << 9) + c0;
    if (r >= 4032) {
        *(f32x4*)(x + base) = (f32x4)0.f;
        *(f32x4*)(x + base + 4) = (f32x4)0.f;
        *(bf8v*)(xb + base) = (bf8v)0;
        return;
    }
    f32x4 a0 = *(const f32x4*)(a + base), a1 = *(const f32x4*)(a + base + 4);
    f32x4 x0 = *(const f32x4*)(x + base), x1 = *(const f32x4*)(x + base + 4);
    float v[8];
#pragma unroll
    for (int i = 0; i < 4; i++) { v[i] = a0[i] + x0[i]; v[4 + i] = a1[i] + x1[i]; }
    float sum = 0.f, sq = 0.f;
#pragma unroll
    for (int i = 0; i < 8; i++) { sum += v[i]; sq += v[i] * v[i]; }
#pragma unroll
    for (int o = 32; o >= 1; o >>= 1) { sum += __shfl_xor(sum, o); sq += __shfl_xor(sq, o); }
    float mean = sum * (1.f / 512.f);
    float var = sq * (1.f / 512.f) - mean * mean;
    float inv = rsqrtf(var + 1e-5f);
    bf8v ob;
#pragma unroll
    for (int i = 0; i < 8; i++) {
        float y = (v[i] - mean) * inv * g[c0 + i] + bb[c0 + i];
        x[base + i] = y;
        ob[i] = f2bf(y);
    }
    *(bf8v*)(xb + base) = ob;
}

// scores [32][128][128] f32 -> P [32][128][128] bf16 with prefix-causal mask
__global__ __launch_bounds__(64) void softmax_k(
    const float* __restrict__ S, ushort_t* __restrict__ P)
{
    int bi = blockIdx.x;
    int row = bi & 127, b = bi >> 7;
    int lane = threadIdx.x;
    long base = (long)(b * 128 + row) << 7;
    if (row >= 126) { P[base + lane] = 0; P[base + lane + 64] = 0; return; }
    float v0 = S[base + lane], v1 = S[base + lane + 64];
    bool a0 = (lane < 50) || (lane <= row);        // j in [0,64)
    int j1 = lane + 64;
    bool a1 = (j1 < 126) && (j1 <= row);           // j in [64,128)
    float m = fmaxf(a0 ? v0 : -3e38f, a1 ? v1 : -3e38f);
#pragma unroll
    for (int o = 32; o >= 1; o >>= 1) m = fmaxf(m, __shfl_xor(m, o));
    float e0 = a0 ? expf(v0 - m) : 0.f;
    float e1 = a1 ? expf(v1 - m) : 0.f;
    float s = e0 + e1;
#pragma unroll
    for (int o = 32; o >= 1; o >>= 1) s += __shfl_xor(s, o);
    float inv = 1.f / s;
    P[base + lane] = f2bf(e0 * inv);
    P[base + lane + 64] = f2bf(e1 * inv);
}

// ---------------------------------------------------------------------------
extern "C" void kernel_launch(void* const* d_in, const int* in_sizes, int n_in,
                              void* d_out, int out_size, void* d_ws, size_t ws_size,
                              hipStream_t stream)
{
    const float* img   = (const float*)d_in[0];   // [32,50,768]
    const int*   cap   = (const int*)  d_in[1];   // [32,76]
    const float* tok   = (const float*)d_in[2];   // [49408,512]
    const float* pos   = (const float*)d_in[3];   // [76,512]
    const float* ff0_w = (const float*)d_in[4];   // [768,512]
    const float* ff0_b = (const float*)d_in[5];
    const float* wq    = (const float*)d_in[6];
    const float* wq_b  = (const float*)d_in[7];
    const float* wk    = (const float*)d_in[8];
    const float* wk_b  = (const float*)d_in[9];
    const float* wv    = (const float*)d_in[10];
    const float* wv_b  = (const float*)d_in[11];
    const float* ln_g  = (const float*)d_in[12];
    const float* ln_b  = (const float*)d_in[13];
    const float* ff1_w = (const float*)d_in[14];
    const float* ff1_b = (const float*)d_in[15];
    const float* ff2_w = (const float*)d_in[16];  // [512,49408]
    const float* ff2_b = (const float*)d_in[17];

    char* ws = (char*)d_ws;
    size_t o = 0;
    auto alloc = [&](size_t bytes) { size_t r = o; o += (bytes + 255) & ~(size_t)255; return r; };

    float*    x    = (float*)   (ws + alloc(4096ull * 512 * 4));
    ushort_t* xb   = (ushort_t*)(ws + alloc(4096ull * 512 * 2));
    float*    tmpf = (float*)   (ws + alloc(4096ull * 512 * 4));  // img_out / attn / fftmp
    ushort_t* qb   = (ushort_t*)(ws + alloc(4096ull * 512 * 2));
    ushort_t* kb   = (ushort_t*)(ws + alloc(4096ull * 512 * 2));
    ushort_t* vtb  = (ushort_t*)(ws + alloc(512ull * 4096 * 2));  // [512][32*128]
    float*    sc   = (float*)   (ws + alloc(32ull * 128 * 128 * 4));
    ushort_t* P    = (ushort_t*)(ws + alloc(32ull * 128 * 128 * 2));
    ushort_t* Atxt = (ushort_t*)(ws + alloc(2560ull * 512 * 2));  // [2560][512]
    ushort_t* Aimg = (ushort_t*)(ws + alloc(1664ull * 768 * 2));  // [1664][768]
    ushort_t* wvT  = (ushort_t*)(ws + alloc(512 * 512 * 2));      // [512][512]
    size_t base_bytes = o;                                         // ~42.4 MB
    size_t ff2T_bytes = 49408ull * 512 * 2;                        // 50.6 MB
    bool use_ff2T = (ws_size >= base_bytes + ff2T_bytes + 256);
    ushort_t* ff2T = use_ff2T ? (ushort_t*)(ws + alloc(ff2T_bytes)) : nullptr;

    const float rsqd = 0.044194173824159216f; // 1/sqrt(512)
    dim3 b32x8(32, 8);

    transpose_bf<<<dim3(16, 16), b32x8, 0, stream>>>(wv, wvT, 512, 512);
    if (use_ff2T)
        transpose_bf<<<dim3(1544, 16), b32x8, 0, stream>>>(ff2_w, ff2T, 512, 49408);
    conv_pad<<<(1664 * 768 + 255) / 256, 256, 0, stream>>>(img, Aimg, 1600, 768, 1664 * 768);

    // ff0: img_out = Aimg @ ff0_w + ff0_b -> tmpf [1600][512]  (B: f32 [768][512])
    gemm_bf16<1><<<dim3(4, 13, 1), 256, 0, stream>>>(
        Aimg, ff0_w, tmpf, nullptr, ff0_b, 768, 768, 512, 512, 0, 0, 0, 1600, 1.f);

    build_x<<<4096, 64, 0, stream>>>(tmpf, cap, tok, pos, ln_g, ln_b, x, xb);

    for (int l = 0; l < 2; l++) {
        gemm_bf16<1><<<dim3(4, 32, 1), 256, 0, stream>>>(
            xb, wq, nullptr, qb, wq_b, 512, 512, 512, 512, 0, 0, 0, 4096, 1.f);
        gemm_bf16<1><<<dim3(4, 32, 1), 256, 0, stream>>>(
            xb, wk, nullptr, kb, wk_b, 512, 512, 512, 512, 0, 0, 0, 4096, 1.f);
        // vT[d][b*128+j] = sum_k wvT[d][k]*xb[b*126+j][k]  (bias folded into PV)
        gemm_bf16<0><<<dim3(1, 4, 32), 256, 0, stream>>>(
            wvT, xb, nullptr, vtb, nullptr, 512, 512, 512, 4096,
            0, (long)126 * 512, 128, 512, 1.f);
        // scores[b] = qb[b] @ kb[b]^T / sqrt(512)
        gemm_bf16<0><<<dim3(1, 1, 32), 256, 0, stream>>>(
            qb, kb, sc, nullptr, nullptr, 512, 512, 512, 128,
            (long)126 * 512, (long)126 * 512, (long)128 * 128, 128, rsqd);
        softmax_k<<<4096, 64, 0, stream>>>(sc, P);
        // attn[b] = P[b] @ V[b] + wv_b  (softmax rows sum to 1 -> bias exact)
        gemm_bf16<0><<<dim3(4, 1, 32), 256, 0, stream>>>(
            P, vtb, tmpf, nullptr, wv_b, 128, 128, 4096, 512,
            (long)128 * 128, 128, (long)126 * 512, 126, 1.f);
        resln<<<4096, 64, 0, stream>>>(tmpf, ln_g, ln_b, x, xb);
        gemm_bf16<1><<<dim3(4, 32, 1), 256, 0, stream>>>(
            xb, ff1_w, tmpf, nullptr, ff1_b, 512, 512, 512, 512, 0, 0, 0, 4032, 1.f);
        resln<<<4096, 64, 0, stream>>>(tmpf, ln_g, ln_b, x, xb);
    }

    gather_txt<<<(2560 * 512 + 255) / 256, 256, 0, stream>>>(xb, Atxt);

    // logits (f32 out): d_out = Atxt @ ff2 + ff2_b
    if (use_ff2T)
        gemm_bf16<0><<<dim3(386, 20, 1), 256, 0, stream>>>(
            Atxt, ff2T, (float*)d_out, nullptr, ff2_b, 512, 512, 512, 49408,
            0, 0, 0, 2432, 1.f);
    else
        gemm_bf16<1><<<dim3(386, 20, 1), 256, 0, stream>>>(
            Atxt, ff2_w, (float*)d_out, nullptr, ff2_b, 512, 512, 49408, 49408,
            0, 0, 0, 2432, 1.f);
}

// Round 7
// 580.291 us; speedup vs baseline: 6.5492x; 1.0657x over previous
//
#include <hip/hip_runtime.h>

typedef unsigned short ushort_t;
typedef __attribute__((ext_vector_type(8))) short short8;
typedef __attribute__((ext_vector_type(4))) float f32x4;
typedef __attribute__((ext_vector_type(4))) unsigned short bf4;
typedef __attribute__((ext_vector_type(8))) unsigned short bf8v;

__device__ __forceinline__ ushort_t f2bf(float f) {
    union { float f; unsigned u; } v; v.f = f;
    unsigned r = v.u + 0x7FFFu + ((v.u >> 16) & 1u);
    return (ushort_t)(r >> 16);
}

#define LDT 72  // padded LDS row stride in ushorts (144 B, 16B-aligned)

// ---------------------------------------------------------------------------
// Batched bf16 GEMM: C[m][n] = scale * sum_k A[m][k]*B'[n][k] + bias[n]
// A: bf16 [M][lda] rows. B operand:
//   BSRC=0: B bf16 [N][ldb] rows (W^T layout), B'[n][k]=B[n][k]
//   BSRC=1: B f32  [K][ldb]  (natural W),      B'[n][k]=B[k][n0+n]
//   BSRC=2: B bf16 [K][ldb]  (natural V),      B'[n][k]=B[k][n0+n]
// tile 128x128, BK=64, 4 waves (2x2), 16x16x32 MFMA, reg->LDS staging.
// SWZ=1: bijective XCD-chunked remap with M-fast order (logits GEMM).
// ---------------------------------------------------------------------------
template <int BSRC, int SWZ>
__global__ __launch_bounds__(256) void gemm_bf16(
    const ushort_t* __restrict__ A, const void* __restrict__ Bv,
    float* __restrict__ C, ushort_t* __restrict__ Cb,
    const float* __restrict__ bias,
    int K, int lda, int ldb, int ldc,
    long sA, long sB, long sC,
    int validM, float scale)
{
    __shared__ __attribute__((aligned(16))) ushort_t As[128 * LDT];
    __shared__ __attribute__((aligned(16))) ushort_t Bs[128 * LDT];

    const int tid = threadIdx.x;
    const int lane = tid & 63;
    const int wave = tid >> 6;
    const int wr = wave >> 1, wc = wave & 1;
    int tN = blockIdx.x, tM = blockIdx.y;
    const int bz = blockIdx.z;
    if (SWZ) {
        const int nwg = gridDim.x * gridDim.y;
        const int lin = blockIdx.x + blockIdx.y * gridDim.x;  // dispatch order
        const int q8 = nwg >> 3, r8 = nwg & 7;
        const int xcd = lin & 7, idx = lin >> 3;
        const int wg = (xcd < r8 ? xcd * (q8 + 1)
                                 : r8 * (q8 + 1) + (xcd - r8) * q8) + idx;
        tM = wg % gridDim.y;                 // M-fast: B panel L2-resident
        tN = wg / gridDim.y;
    }
    const int n0 = tN * 128;

    const ushort_t* Abase = A + (long)bz * sA + (long)tM * 128 * lda;
    const ushort_t* Bb = (BSRC == 0)
        ? (const ushort_t*)Bv + (long)bz * sB + (long)n0 * ldb : nullptr;
    const float* Bf = (BSRC == 1)
        ? (const float*)Bv + (long)bz * sB : nullptr;
    const ushort_t* Bb2 = (BSRC == 2)
        ? (const ushort_t*)Bv + (long)bz * sB : nullptr;

    f32x4 acc[4][4];
#pragma unroll
    for (int m = 0; m < 4; m++)
#pragma unroll
        for (int n = 0; n < 4; n++) acc[m][n] = (f32x4)0.f;

    for (int ks = 0; ks < K; ks += 64) {
        // ---- global loads into registers ----
        short8 ar[4];
#pragma unroll
        for (int i = 0; i < 4; i++) {
            int ch = wave * 256 + i * 64 + lane;   // 16B-chunk id in [0,1024)
            int row = ch >> 3, c16 = ch & 7;
            ar[i] = *(const short8*)(Abase + (long)row * lda + ks + (c16 << 3));
        }
        short8 br[4];
        bf4 pk[8];
        if (BSRC == 0) {
#pragma unroll
            for (int i = 0; i < 4; i++) {
                int ch = wave * 256 + i * 64 + lane;
                int row = ch >> 3, c16 = ch & 7;
                br[i] = *(const short8*)(Bb + (long)row * ldb + ks + (c16 << 3));
            }
        } else if (BSRC == 1) {
#pragma unroll
            for (int q = 0; q < 8; q++) {
                int qid = q * 256 + tid;           // [0,2048)
                int n = qid & 127, kq = qid >> 7;  // kq in [0,16)
                const float* wp = Bf + (long)(ks + kq * 4) * ldb + n0 + n;
                bf4 p;
                p[0] = f2bf(wp[0]);
                p[1] = f2bf(wp[ldb]);
                p[2] = f2bf(wp[2 * (long)ldb]);
                p[3] = f2bf(wp[3 * (long)ldb]);
                pk[q] = p;
            }
        } else {
#pragma unroll
            for (int q = 0; q < 8; q++) {
                int qid = q * 256 + tid;
                int n = qid & 127, kq = qid >> 7;
                const ushort_t* wp = Bb2 + (long)(ks + kq * 4) * ldb + n0 + n;
                bf4 p;
                p[0] = wp[0];
                p[1] = wp[ldb];
                p[2] = wp[2 * (long)ldb];
                p[3] = wp[3 * (long)ldb];
                pk[q] = p;
            }
        }

        if (ks) __syncthreads();   // previous tile's readers done

        // ---- LDS writes ----
#pragma unroll
        for (int i = 0; i < 4; i++) {
            int ch = wave * 256 + i * 64 + lane;
            int row = ch >> 3, c16 = ch & 7;
            *(short8*)(As + row * LDT + (c16 << 3)) = ar[i];
        }
        if (BSRC == 0) {
#pragma unroll
            for (int i = 0; i < 4; i++) {
                int ch = wave * 256 + i * 64 + lane;
                int row = ch >> 3, c16 = ch & 7;
                *(short8*)(Bs + row * LDT + (c16 << 3)) = br[i];
            }
        } else {
#pragma unroll
            for (int q = 0; q < 8; q++) {
                int qid = q * 256 + tid;
                int n = qid & 127, kq = qid >> 7;
                *(bf4*)(Bs + n * LDT + (kq << 2)) = pk[q];
            }
        }
        __syncthreads();

        // ---- MFMA ----
#pragma unroll
        for (int ksub = 0; ksub < 2; ksub++) {
            const int kk = ksub * 32 + ((lane >> 4) << 3);
            short8 af[4], bfr[4];
#pragma unroll
            for (int m = 0; m < 4; m++)
                af[m] = *(const short8*)(As + ((wr << 6) + m * 16 + (lane & 15)) * LDT + kk);
#pragma unroll
            for (int n = 0; n < 4; n++)
                bfr[n] = *(const short8*)(Bs + ((wc << 6) + n * 16 + (lane & 15)) * LDT + kk);
#pragma unroll
            for (int m = 0; m < 4; m++)
#pragma unroll
                for (int n = 0; n < 4; n++)
                    acc[m][n] = __builtin_amdgcn_mfma_f32_16x16x32_bf16(
                        af[m], bfr[n], acc[m][n], 0, 0, 0);
        }
        if (ks + 64 < K) __syncthreads();
    }

    const int rb = (wr << 6) + ((lane >> 4) << 2);
    const int cb = (wc << 6) + (lane & 15);
#pragma unroll
    for (int m = 0; m < 4; m++) {
#pragma unroll
        for (int i = 0; i < 4; i++) {
            int r = tM * 128 + rb + m * 16 + i;
            if (r >= validM) continue;
#pragma unroll
            for (int n = 0; n < 4; n++) {
                int cg = n0 + cb + n * 16;
                float v = acc[m][n][i] * scale + (bias ? bias[cg] : 0.f);
                long off = (long)bz * sC + (long)r * ldc + cg;
                if (C) C[off] = v;
                if (Cb) Cb[off] = f2bf(v);
            }
        }
    }
}

// ---------------------------------------------------------------------------
// transpose f32 [R][C] -> bf16 [C][R]
// ---------------------------------------------------------------------------
__global__ __launch_bounds__(256) void transpose_bf(
    const float* __restrict__ in, ushort_t* __restrict__ out, int R, int C)
{
    __shared__ float t[32][33];
    int c0 = blockIdx.x << 5, r0 = blockIdx.y << 5;
    int tx = threadIdx.x, ty = threadIdx.y;
#pragma unroll
    for (int i = 0; i < 4; i++)
        t[ty + i * 8][tx] = in[(long)(r0 + ty + i * 8) * C + c0 + tx];
    __syncthreads();
#pragma unroll
    for (int i = 0; i < 4; i++)
        out[(long)(c0 + ty + i * 8) * R + r0 + tx] = f2bf(t[tx][ty + i * 8]);
}

// concat 3 x [512] f32 bias vectors
__global__ __launch_bounds__(256) void biascat(
    const float* __restrict__ b0, const float* __restrict__ b1,
    const float* __restrict__ b2, float* __restrict__ out)
{
    int i = blockIdx.x * 256 + threadIdx.x;  // [0,1536)
    const float* s = (i < 512) ? b0 : (i < 1024) ? b1 : b2;
    out[i] = s[i & 511];
}

// f32 [validR][C] -> bf16 [Rpad][C] with zero pad
__global__ __launch_bounds__(256) void conv_pad(
    const float* __restrict__ in, ushort_t* __restrict__ out,
    int validR, int C, int total)
{
    int idx = blockIdx.x * 256 + threadIdx.x;
    if (idx >= total) return;
    int r = idx / C;
    float v = 0.f;
    if (r < validR) v = in[idx];
    out[idx] = f2bf(v);
}

// gather final-LN bf16 rows for txt positions -> Atxt [2560][512] (pad zero)
__global__ __launch_bounds__(256) void gather_txt(
    const ushort_t* __restrict__ xb, ushort_t* __restrict__ At)
{
    int idx = blockIdx.x * 256 + threadIdx.x;
    if (idx >= 2560 * 512) return;
    int r = idx >> 9, c = idx & 511;
    if (r < 2432) {
        int b = r / 76, t = r - b * 76;
        At[idx] = xb[((long)(b * 126 + 50 + t) << 9) + c];
    } else {
        At[idx] = 0;
    }
}

// build x = LN(concat(img_out, tok_emb[cap]+pos)) ; rows >= 4032 zeroed
__global__ __launch_bounds__(64) void build_x(
    const float* __restrict__ imgout, const int* __restrict__ cap,
    const float* __restrict__ tok, const float* __restrict__ pos,
    const float* __restrict__ g, const float* __restrict__ bb,
    float* __restrict__ x, ushort_t* __restrict__ xb)
{
    int r = blockIdx.x, lane = threadIdx.x;
    int c0 = lane << 3;
    long base = ((long)r << 9) + c0;
    if (r >= 4032) {
        *(f32x4*)(x + base) = (f32x4)0.f;
        *(f32x4*)(x + base + 4) = (f32x4)0.f;
        *(bf8v*)(xb + base) = (bf8v)0;
        return;
    }
    int b = r / 126, s = r - b * 126;
    float v[8];
    if (s < 50) {
        const float* src = imgout + ((long)(b * 50 + s) << 9) + c0;
        f32x4 a0 = *(const f32x4*)src, a1 = *(const f32x4*)(src + 4);
#pragma unroll
        for (int i = 0; i < 4; i++) { v[i] = a0[i]; v[4 + i] = a1[i]; }
    } else {
        int t = s - 50;
        int id = cap[b * 76 + t];
        const float* s1 = tok + ((long)id << 9) + c0;
        const float* s2 = pos + ((long)t << 9) + c0;
        f32x4 a0 = *(const f32x4*)s1, a1 = *(const f32x4*)(s1 + 4);
        f32x4 b0 = *(const f32x4*)s2, b1 = *(const f32x4*)(s2 + 4);
#pragma unroll
        for (int i = 0; i < 4; i++) { v[i] = a0[i] + b0[i]; v[4 + i] = a1[i] + b1[i]; }
    }
    float sum = 0.f, sq = 0.f;
#pragma unroll
    for (int i = 0; i < 8; i++) { sum += v[i]; sq += v[i] * v[i]; }
#pragma unroll
    for (int o = 32; o >= 1; o >>= 1) { sum += __shfl_xor(sum, o); sq += __shfl_xor(sq, o); }
    float mean = sum * (1.f / 512.f);
    float var = sq * (1.f / 512.f) - mean * mean;
    float inv = rsqrtf(var + 1e-5f);
    bf8v ob;
#pragma unroll
    for (int i = 0; i < 8; i++) {
        float y = (v[i] - mean) * inv * g[c0 + i] + bb[c0 + i];
        x[base + i] = y;
        ob[i] = f2bf(y);
    }
    *(bf8v*)(xb + base) = ob;
}

// x = LN(a + x) ; rows >= 4032 zeroed
__global__ __launch_bounds__(64) void resln(
    const float* __restrict__ a, const float* __restrict__ g,
    const float* __restrict__ bb, float* __restrict__ x, ushort_t* __restrict__ xb)
{
    int r = blockIdx.x, lane = threadIdx.x;
    int c0 = lane << 3;
    long base = ((long)r << 9) + c0;
    if (r >= 4032) {
        *(f32x4*)(x + base) = (f32x4)0.f;
        *(f32x4*)(x + base + 4) = (f32x4)0.f;
        *(bf8v*)(xb + base) = (bf8v)0;
        return;
    }
    f32x4 a0 = *(const f32x4*)(a + base), a1 = *(const f32x4*)(a + base + 4);
    f32x4 x0 = *(const f32x4*)(x + base), x1 = *(const f32x4*)(x + base + 4);
    float v[8];
#pragma unroll
    for (int i = 0; i < 4; i++) { v[i] = a0[i] + x0[i]; v[4 + i] = a1[i] + x1[i]; }
    float sum = 0.f, sq = 0.f;
#pragma unroll
    for (int i = 0; i < 8; i++) { sum += v[i]; sq += v[i] * v[i]; }
#pragma unroll
    for (int o = 32; o >= 1; o >>= 1) { sum += __shfl_xor(sum, o); sq += __shfl_xor(sq, o); }
    float mean = sum * (1.f / 512.f);
    float var = sq * (1.f / 512.f) - mean * mean;
    float inv = rsqrtf(var + 1e-5f);
    bf8v ob;
#pragma unroll
    for (int i = 0; i < 8; i++) {
        float y = (v[i] - mean) * inv * g[c0 + i] + bb[c0 + i];
        x[base + i] = y;
        ob[i] = f2bf(y);
    }
    *(bf8v*)(xb + base) = ob;
}

// scores [32][128][128] f32 -> P [32][128][128] bf16 with prefix-causal mask
__global__ __launch_bounds__(64) void softmax_k(
    const float* __restrict__ S, ushort_t* __restrict__ P)
{
    int bi = blockIdx.x;
    int row = bi & 127, b = bi >> 7;
    int lane = threadIdx.x;
    long base = (long)(b * 128 + row) << 7;
    if (row >= 126) { P[base + lane] = 0; P[base + lane + 64] = 0; return; }
    float v0 = S[base + lane], v1 = S[base + lane + 64];
    bool a0 = (lane < 50) || (lane <= row);        // j in [0,64)
    int j1 = lane + 64;
    bool a1 = (j1 < 126) && (j1 <= row);           // j in [64,128)
    float m = fmaxf(a0 ? v0 : -3e38f, a1 ? v1 : -3e38f);
#pragma unroll
    for (int o = 32; o >= 1; o >>= 1) m = fmaxf(m, __shfl_xor(m, o));
    float e0 = a0 ? expf(v0 - m) : 0.f;
    float e1 = a1 ? expf(v1 - m) : 0.f;
    float s = e0 + e1;
#pragma unroll
    for (int o = 32; o >= 1; o >>= 1) s += __shfl_xor(s, o);
    float inv = 1.f / s;
    P[base + lane] = f2bf(e0 * inv);
    P[base + lane + 64] = f2bf(e1 * inv);
}

// ---------------------------------------------------------------------------
extern "C" void kernel_launch(void* const* d_in, const int* in_sizes, int n_in,
                              void* d_out, int out_size, void* d_ws, size_t ws_size,
                              hipStream_t stream)
{
    const float* img   = (const float*)d_in[0];   // [32,50,768]
    const int*   cap   = (const int*)  d_in[1];   // [32,76]
    const float* tok   = (const float*)d_in[2];   // [49408,512]
    const float* pos   = (const float*)d_in[3];   // [76,512]
    const float* ff0_w = (const float*)d_in[4];   // [768,512]
    const float* ff0_b = (const float*)d_in[5];
    const float* wq    = (const float*)d_in[6];
    const float* wq_b  = (const float*)d_in[7];
    const float* wk    = (const float*)d_in[8];
    const float* wk_b  = (const float*)d_in[9];
    const float* wv    = (const float*)d_in[10];
    const float* wv_b  = (const float*)d_in[11];
    const float* ln_g  = (const float*)d_in[12];
    const float* ln_b  = (const float*)d_in[13];
    const float* ff1_w = (const float*)d_in[14];
    const float* ff1_b = (const float*)d_in[15];
    const float* ff2_w = (const float*)d_in[16];  // [512,49408]
    const float* ff2_b = (const float*)d_in[17];

    char* ws = (char*)d_ws;
    size_t o = 0;
    auto alloc = [&](size_t bytes) { size_t r = o; o += (bytes + 255) & ~(size_t)255; return r; };

    float*    x     = (float*)   (ws + alloc(4096ull * 512 * 4));
    ushort_t* xb    = (ushort_t*)(ws + alloc(4096ull * 512 * 2));
    float*    tmpf  = (float*)   (ws + alloc(4096ull * 512 * 4));   // img_out / attn / fftmp
    ushort_t* qkvb  = (ushort_t*)(ws + alloc(4096ull * 1536 * 2));  // [4096][q|k|v]
    float*    sc    = (float*)   (ws + alloc(32ull * 128 * 128 * 4));
    ushort_t* P     = (ushort_t*)(ws + alloc(32ull * 128 * 128 * 2));
    ushort_t* Atxt  = (ushort_t*)(ws + alloc(2560ull * 512 * 2));
    ushort_t* Aimg  = (ushort_t*)(ws + alloc(1664ull * 768 * 2));
    ushort_t* wqkvT = (ushort_t*)(ws + alloc(1536ull * 512 * 2));   // [wqT;wkT;wvT]
    float*    bcat  = (float*)   (ws + alloc(1536 * 4));
    size_t base_bytes = o;                                           // ~44 MB
    size_t ff2T_bytes = 49408ull * 512 * 2;                          // 50.6 MB
    bool use_ff2T = (ws_size >= base_bytes + ff2T_bytes + 256);
    ushort_t* ff2T = use_ff2T ? (ushort_t*)(ws + alloc(ff2T_bytes)) : nullptr;

    const float rsqd = 0.044194173824159216f; // 1/sqrt(512)
    const ushort_t* qb = qkvb;
    const ushort_t* kb = qkvb + 512;
    const ushort_t* vb = qkvb + 1024;
    dim3 b32x8(32, 8);

    transpose_bf<<<dim3(16, 16), b32x8, 0, stream>>>(wq, wqkvT, 512, 512);
    transpose_bf<<<dim3(16, 16), b32x8, 0, stream>>>(wk, wqkvT + 512 * 512, 512, 512);
    transpose_bf<<<dim3(16, 16), b32x8, 0, stream>>>(wv, wqkvT + 1024 * 512, 512, 512);
    biascat<<<6, 256, 0, stream>>>(wq_b, wk_b, wv_b, bcat);
    if (use_ff2T)
        transpose_bf<<<dim3(1544, 16), b32x8, 0, stream>>>(ff2_w, ff2T, 512, 49408);
    conv_pad<<<(1664 * 768 + 255) / 256, 256, 0, stream>>>(img, Aimg, 1600, 768, 1664 * 768);

    // ff0: img_out = Aimg @ ff0_w + ff0_b -> tmpf [1600][512]  (B: f32 [768][512])
    gemm_bf16<1, 0><<<dim3(4, 13, 1), 256, 0, stream>>>(
        Aimg, ff0_w, tmpf, nullptr, ff0_b, 768, 768, 512, 512, 0, 0, 0, 1600, 1.f);

    build_x<<<4096, 64, 0, stream>>>(tmpf, cap, tok, pos, ln_g, ln_b, x, xb);

    for (int l = 0; l < 2; l++) {
        // fused qkv: [4096][1536] = xb @ WqkvT^T + bcat   (wv_b included in V)
        gemm_bf16<0, 0><<<dim3(12, 32, 1), 256, 0, stream>>>(
            xb, wqkvT, nullptr, qkvb, bcat, 512, 512, 512, 1536, 0, 0, 0, 4096, 1.f);
        // scores[b] = q[b] @ k[b]^T / sqrt(512)
        gemm_bf16<0, 0><<<dim3(1, 1, 32), 256, 0, stream>>>(
            qb, kb, sc, nullptr, nullptr, 512, 1536, 1536, 128,
            (long)126 * 1536, (long)126 * 1536, (long)128 * 128, 128, rsqd);
        softmax_k<<<4096, 64, 0, stream>>>(sc, P);
        // attn[b] = P[b] @ V[b]   (V natural layout, BSRC=2; bias already in V)
        gemm_bf16<2, 0><<<dim3(4, 1, 32), 256, 0, stream>>>(
            P, vb, tmpf, nullptr, nullptr, 128, 128, 1536, 512,
            (long)128 * 128, (long)126 * 1536, (long)126 * 512, 126, 1.f);
        resln<<<4096, 64, 0, stream>>>(tmpf, ln_g, ln_b, x, xb);
        gemm_bf16<1, 0><<<dim3(4, 32, 1), 256, 0, stream>>>(
            xb, ff1_w, tmpf, nullptr, ff1_b, 512, 512, 512, 512, 0, 0, 0, 4032, 1.f);
        resln<<<4096, 64, 0, stream>>>(tmpf, ln_g, ln_b, x, xb);
    }

    gather_txt<<<(2560 * 512 + 255) / 256, 256, 0, stream>>>(xb, Atxt);

    // logits (f32 out): d_out = Atxt @ ff2 + ff2_b, XCD-chunked M-fast swizzle
    if (use_ff2T)
        gemm_bf16<0, 1><<<dim3(386, 20, 1), 256, 0, stream>>>(
            Atxt, ff2T, (float*)d_out, nullptr, ff2_b, 512, 512, 512, 49408,
            0, 0, 0, 2432, 1.f);
    else
        gemm_bf16<1, 1><<<dim3(386, 20, 1), 256, 0, stream>>>(
            Atxt, ff2_w, (float*)d_out, nullptr, ff2_b, 512, 512, 49408, 49408,
            0, 0, 0, 2432, 1.f);
}

// Round 8
// 577.024 us; speedup vs baseline: 6.5863x; 1.0057x over previous
//
#include <hip/hip_runtime.h>

typedef unsigned short ushort_t;
typedef __attribute__((ext_vector_type(8))) short short8;
typedef __attribute__((ext_vector_type(4))) float f32x4;
typedef __attribute__((ext_vector_type(4))) unsigned short bf4;
typedef __attribute__((ext_vector_type(8))) unsigned short bf8v;

__device__ __forceinline__ ushort_t f2bf(float f) {
    union { float f; unsigned u; } v; v.f = f;
    unsigned r = v.u + 0x7FFFu + ((v.u >> 16) & 1u);
    return (ushort_t)(r >> 16);
}

__device__ __forceinline__ void g2lds16(const ushort_t* g, ushort_t* l) {
    __builtin_amdgcn_global_load_lds(
        (const __attribute__((address_space(1))) void*)g,
        (__attribute__((address_space(3))) void*)l, 16, 0, 0);
}

#define LDT 72  // padded LDS row stride (reg-staged paths)

// ---------------------------------------------------------------------------
// Batched bf16 GEMM: C[m][n] = scale * sum_k A[m][k]*B'[n][k] + bias[n]
//   BSRC=0: B bf16 [N][ldb] rows (W^T). global_load_lds staging, linear LDS.
//           (structure == round-1 kernel, numerically validated vs reference)
//   BSRC=1: B f32  [K][ldb] natural W. reg-staged (fallback only).
//   BSRC=2: B bf16 [K][ldb] natural V. reg-staged.
// tile 128x128, BK=64, 4 waves (2x2), 16x16x32 MFMA.
// SWZ=1: grouped-N(8) rasterization: inner n-fast over 8 cols (== NXCD,
//        round-robin -> each XCD owns one tN per group), then tM. B+A stay
//        L2-resident per XCD; adjacent concurrent blocks write adjacent cols.
// ---------------------------------------------------------------------------
template <int BSRC, int SWZ>
__global__ __launch_bounds__(256) void gemm_bf16(
    const ushort_t* __restrict__ A, const void* __restrict__ Bv,
    float* __restrict__ C, ushort_t* __restrict__ Cb,
    const float* __restrict__ bias,
    int K, int lda, int ldb, int ldc,
    long sA, long sB, long sC,
    int validM, float scale)
{
    constexpr int LS = (BSRC == 0) ? 64 : LDT;   // LDS row stride
    __shared__ __attribute__((aligned(16))) ushort_t As[128 * LS];
    __shared__ __attribute__((aligned(16))) ushort_t Bs[128 * LS];

    const int tid = threadIdx.x;
    const int lane = tid & 63;
    const int wave = tid >> 6;
    const int wr = wave >> 1, wc = wave & 1;
    int tN = blockIdx.x, tM = blockIdx.y;
    const int bz = blockIdx.z;
    if (SWZ) {
        const int lin = blockIdx.x + blockIdx.y * gridDim.x;
        const int TM = gridDim.y;
        const int full = gridDim.x >> 3;         // full groups of 8 columns
        const int per = TM << 3;                 // blocks per full group
        const int g = lin / per;
        if (g < full) {
            const int rem = lin - g * per;
            tM = rem >> 3;
            tN = (g << 3) + (rem & 7);
        } else {
            const int rem = lin - full * per;
            const int w = gridDim.x - (full << 3);
            tM = rem / w;
            tN = (full << 3) + rem - tM * w;
        }
    }
    const int n0 = tN * 128;

    const ushort_t* Abase = A + (long)bz * sA + (long)tM * 128 * lda;
    const ushort_t* Bb = (BSRC == 0)
        ? (const ushort_t*)Bv + (long)bz * sB + (long)n0 * ldb : nullptr;
    const float* Bf = (BSRC == 1)
        ? (const float*)Bv + (long)bz * sB : nullptr;
    const ushort_t* Bb2 = (BSRC == 2)
        ? (const ushort_t*)Bv + (long)bz * sB : nullptr;

    f32x4 acc[4][4];
#pragma unroll
    for (int m = 0; m < 4; m++)
#pragma unroll
        for (int n = 0; n < 4; n++) acc[m][n] = (f32x4)0.f;

    for (int ks = 0; ks < K; ks += 64) {
        if (BSRC == 0) {
            // -------- direct global->LDS staging (m97 structure) --------
            if (ks) __syncthreads();             // readers of prev tile done
#pragma unroll
            for (int i = 0; i < 4; i++) {
                int ch = wave * 256 + i * 64 + lane;    // 16B chunk id
                int row = ch >> 3, c16 = ch & 7;
                g2lds16(Abase + (long)row * lda + ks + (c16 << 3),
                        As + (wave * 256 + i * 64) * 8);
            }
#pragma unroll
            for (int i = 0; i < 4; i++) {
                int ch = wave * 256 + i * 64 + lane;
                int row = ch >> 3, c16 = ch & 7;
                g2lds16(Bb + (long)row * ldb + ks + (c16 << 3),
                        Bs + (wave * 256 + i * 64) * 8);
            }
            asm volatile("s_waitcnt vmcnt(0)" ::: "memory");
            __syncthreads();
        } else {
            // -------- reg-staged path (validated round-3/7 structure) ----
            short8 ar[4];
#pragma unroll
            for (int i = 0; i < 4; i++) {
                int ch = wave * 256 + i * 64 + lane;
                int row = ch >> 3, c16 = ch & 7;
                ar[i] = *(const short8*)(Abase + (long)row * lda + ks + (c16 << 3));
            }
            bf4 pk[8];
            if (BSRC == 1) {
#pragma unroll
                for (int q = 0; q < 8; q++) {
                    int qid = q * 256 + tid;
                    int n = qid & 127, kq = qid >> 7;
                    const float* wp = Bf + (long)(ks + kq * 4) * ldb + n0 + n;
                    bf4 p;
                    p[0] = f2bf(wp[0]);
                    p[1] = f2bf(wp[ldb]);
                    p[2] = f2bf(wp[2 * (long)ldb]);
                    p[3] = f2bf(wp[3 * (long)ldb]);
                    pk[q] = p;
                }
            } else {
#pragma unroll
                for (int q = 0; q < 8; q++) {
                    int qid = q * 256 + tid;
                    int n = qid & 127, kq = qid >> 7;
                    const ushort_t* wp = Bb2 + (long)(ks + kq * 4) * ldb + n0 + n;
                    bf4 p;
                    p[0] = wp[0];
                    p[1] = wp[ldb];
                    p[2] = wp[2 * (long)ldb];
                    p[3] = wp[3 * (long)ldb];
                    pk[q] = p;
                }
            }
            if (ks) __syncthreads();
#pragma unroll
            for (int i = 0; i < 4; i++) {
                int ch = wave * 256 + i * 64 + lane;
                int row = ch >> 3, c16 = ch & 7;
                *(short8*)(As + row * LS + (c16 << 3)) = ar[i];
            }
#pragma unroll
            for (int q = 0; q < 8; q++) {
                int qid = q * 256 + tid;
                int n = qid & 127, kq = qid >> 7;
                *(bf4*)(Bs + n * LS + (kq << 2)) = pk[q];
            }
            __syncthreads();
        }

        // ---- MFMA ----
#pragma unroll
        for (int ksub = 0; ksub < 2; ksub++) {
            const int kk = ksub * 32 + ((lane >> 4) << 3);
            short8 af[4], bfr[4];
#pragma unroll
            for (int m = 0; m < 4; m++)
                af[m] = *(const short8*)(As + ((wr << 6) + m * 16 + (lane & 15)) * LS + kk);
#pragma unroll
            for (int n = 0; n < 4; n++)
                bfr[n] = *(const short8*)(Bs + ((wc << 6) + n * 16 + (lane & 15)) * LS + kk);
#pragma unroll
            for (int m = 0; m < 4; m++)
#pragma unroll
                for (int n = 0; n < 4; n++)
                    acc[m][n] = __builtin_amdgcn_mfma_f32_16x16x32_bf16(
                        af[m], bfr[n], acc[m][n], 0, 0, 0);
        }
        if (BSRC != 0 && ks + 64 < K) __syncthreads();
    }

    const int rb = (wr << 6) + ((lane >> 4) << 2);
    const int cb = (wc << 6) + (lane & 15);
#pragma unroll
    for (int m = 0; m < 4; m++) {
#pragma unroll
        for (int i = 0; i < 4; i++) {
            int r = tM * 128 + rb + m * 16 + i;
            if (r >= validM) continue;
#pragma unroll
            for (int n = 0; n < 4; n++) {
                int cg = n0 + cb + n * 16;
                float v = acc[m][n][i] * scale + (bias ? bias[cg] : 0.f);
                long off = (long)bz * sC + (long)r * ldc + cg;
                if (C) C[off] = v;
                if (Cb) Cb[off] = f2bf(v);
            }
        }
    }
}

// ---------------------------------------------------------------------------
// transpose f32 [R][C] -> bf16 [C][R]
// ---------------------------------------------------------------------------
__global__ __launch_bounds__(256) void transpose_bf(
    const float* __restrict__ in, ushort_t* __restrict__ out, int R, int C)
{
    __shared__ float t[32][33];
    int c0 = blockIdx.x << 5, r0 = blockIdx.y << 5;
    int tx = threadIdx.x, ty = threadIdx.y;
#pragma unroll
    for (int i = 0; i < 4; i++)
        t[ty + i * 8][tx] = in[(long)(r0 + ty + i * 8) * C + c0 + tx];
    __syncthreads();
#pragma unroll
    for (int i = 0; i < 4; i++)
        out[(long)(c0 + ty + i * 8) * R + r0 + tx] = f2bf(t[tx][ty + i * 8]);
}

// concat 3 x [512] f32 bias vectors
__global__ __launch_bounds__(256) void biascat(
    const float* __restrict__ b0, const float* __restrict__ b1,
    const float* __restrict__ b2, float* __restrict__ out)
{
    int i = blockIdx.x * 256 + threadIdx.x;  // [0,1536)
    const float* s = (i < 512) ? b0 : (i < 1024) ? b1 : b2;
    out[i] = s[i & 511];
}

// f32 [validR][C] -> bf16 [Rpad][C] with zero pad
__global__ __launch_bounds__(256) void conv_pad(
    const float* __restrict__ in, ushort_t* __restrict__ out,
    int validR, int C, int total)
{
    int idx = blockIdx.x * 256 + threadIdx.x;
    if (idx >= total) return;
    int r = idx / C;
    float v = 0.f;
    if (r < validR) v = in[idx];
    out[idx] = f2bf(v);
}

// gather final-LN bf16 rows for txt positions -> Atxt [2560][512] (pad zero)
__global__ __launch_bounds__(256) void gather_txt(
    const ushort_t* __restrict__ xb, ushort_t* __restrict__ At)
{
    int idx = blockIdx.x * 256 + threadIdx.x;
    if (idx >= 2560 * 512) return;
    int r = idx >> 9, c = idx & 511;
    if (r < 2432) {
        int b = r / 76, t = r - b * 76;
        At[idx] = xb[((long)(b * 126 + 50 + t) << 9) + c];
    } else {
        At[idx] = 0;
    }
}

// build x = LN(concat(img_out, tok_emb[cap]+pos)) ; rows >= 4032 zeroed
__global__ __launch_bounds__(64) void build_x(
    const float* __restrict__ imgout, const int* __restrict__ cap,
    const float* __restrict__ tok, const float* __restrict__ pos,
    const float* __restrict__ g, const float* __restrict__ bb,
    float* __restrict__ x, ushort_t* __restrict__ xb)
{
    int r = blockIdx.x, lane = threadIdx.x;
    int c0 = lane << 3;
    long base = ((long)r << 9) + c0;
    if (r >= 4032) {
        *(f32x4*)(x + base) = (f32x4)0.f;
        *(f32x4*)(x + base + 4) = (f32x4)0.f;
        *(bf8v*)(xb + base) = (bf8v)0;
        return;
    }
    int b = r / 126, s = r - b * 126;
    float v[8];
    if (s < 50) {
        const float* src = imgout + ((long)(b * 50 + s) << 9) + c0;
        f32x4 a0 = *(const f32x4*)src, a1 = *(const f32x4*)(src + 4);
#pragma unroll
        for (int i = 0; i < 4; i++) { v[i] = a0[i]; v[4 + i] = a1[i]; }
    } else {
        int t = s - 50;
        int id = cap[b * 76 + t];
        const float* s1 = tok + ((long)id << 9) + c0;
        const float* s2 = pos + ((long)t << 9) + c0;
        f32x4 a0 = *(const f32x4*)s1, a1 = *(const f32x4*)(s1 + 4);
        f32x4 b0 = *(const f32x4*)s2, b1 = *(const f32x4*)(s2 + 4);
#pragma unroll
        for (int i = 0; i < 4; i++) { v[i] = a0[i] + b0[i]; v[4 + i] = a1[i] + b1[i]; }
    }
    float sum = 0.f, sq = 0.f;
#pragma unroll
    for (int i = 0; i < 8; i++) { sum += v[i]; sq += v[i] * v[i]; }
#pragma unroll
    for (int o = 32; o >= 1; o >>= 1) { sum += __shfl_xor(sum, o); sq += __shfl_xor(sq, o); }
    float mean = sum * (1.f / 512.f);
    float var = sq * (1.f / 512.f) - mean * mean;
    float inv = rsqrtf(var + 1e-5f);
    bf8v ob;
#pragma unroll
    for (int i = 0; i < 8; i++) {
        float y = (v[i] - mean) * inv * g[c0 + i] + bb[c0 + i];
        x[base + i] = y;
        ob[i] = f2bf(y);
    }
    *(bf8v*)(xb + base) = ob;
}

// x = LN(a + x) ; rows >= 4032 zeroed
__global__ __launch_bounds__(64) void resln(
    const float* __restrict__ a, const float* __restrict__ g,
    const float* __restrict__ bb, float* __restrict__ x, ushort_t* __restrict__ xb)
{
    int r = blockIdx.x, lane = threadIdx.x;
    int c0 = lane << 3;
    long base = ((long)r << 9) + c0;
    if (r >= 4032) {
        *(f32x4*)(x + base) = (f32x4)0.f;
        *(f32x4*)(x + base + 4) = (f32x4)0.f;
        *(bf8v*)(xb + base) = (bf8v)0;
        return;
    }
    f32x4 a0 = *(const f32x4*)(a + base), a1 = *(const f32x4*)(a + base + 4);
    f32x4 x0 = *(const f32x4*)(x + base), x1 = *(const f32x4*)(x + base + 4);
    float v[8];
#pragma unroll
    for (int i = 0; i < 4; i++) { v[i] = a0[i] + x0[i]; v[4 + i] = a1[i] + x1[i]; }
    float sum = 0.f, sq = 0.f;
#pragma unroll
    for (int i = 0; i < 8; i++) { sum += v[i]; sq += v[i] * v[i]; }
#pragma unroll
    for (int o = 32; o >= 1; o >>= 1) { sum += __shfl_xor(sum, o); sq += __shfl_xor(sq, o); }
    float mean = sum * (1.f / 512.f);
    float var = sq * (1.f / 512.f) - mean * mean;
    float inv = rsqrtf(var + 1e-5f);
    bf8v ob;
#pragma unroll
    for (int i = 0; i < 8; i++) {
        float y = (v[i] - mean) * inv * g[c0 + i] + bb[c0 + i];
        x[base + i] = y;
        ob[i] = f2bf(y);
    }
    *(bf8v*)(xb + base) = ob;
}

// scores [32][128][128] f32 -> P [32][128][128] bf16 with prefix-causal mask
__global__ __launch_bounds__(64) void softmax_k(
    const float* __restrict__ S, ushort_t* __restrict__ P)
{
    int bi = blockIdx.x;
    int row = bi & 127, b = bi >> 7;
    int lane = threadIdx.x;
    long base = (long)(b * 128 + row) << 7;
    if (row >= 126) { P[base + lane] = 0; P[base + lane + 64] = 0; return; }
    float v0 = S[base + lane], v1 = S[base + lane + 64];
    bool a0 = (lane < 50) || (lane <= row);        // j in [0,64)
    int j1 = lane + 64;
    bool a1 = (j1 < 126) && (j1 <= row);           // j in [64,128)
    float m = fmaxf(a0 ? v0 : -3e38f, a1 ? v1 : -3e38f);
#pragma unroll
    for (int o = 32; o >= 1; o >>= 1) m = fmaxf(m, __shfl_xor(m, o));
    float e0 = a0 ? expf(v0 - m) : 0.f;
    float e1 = a1 ? expf(v1 - m) : 0.f;
    float s = e0 + e1;
#pragma unroll
    for (int o = 32; o >= 1; o >>= 1) s += __shfl_xor(s, o);
    float inv = 1.f / s;
    P[base + lane] = f2bf(e0 * inv);
    P[base + lane + 64] = f2bf(e1 * inv);
}

// ---------------------------------------------------------------------------
extern "C" void kernel_launch(void* const* d_in, const int* in_sizes, int n_in,
                              void* d_out, int out_size, void* d_ws, size_t ws_size,
                              hipStream_t stream)
{
    const float* img   = (const float*)d_in[0];   // [32,50,768]
    const int*   cap   = (const int*)  d_in[1];   // [32,76]
    const float* tok   = (const float*)d_in[2];   // [49408,512]
    const float* pos   = (const float*)d_in[3];   // [76,512]
    const float* ff0_w = (const float*)d_in[4];   // [768,512]
    const float* ff0_b = (const float*)d_in[5];
    const float* wq    = (const float*)d_in[6];
    const float* wq_b  = (const float*)d_in[7];
    const float* wk    = (const float*)d_in[8];
    const float* wk_b  = (const float*)d_in[9];
    const float* wv    = (const float*)d_in[10];
    const float* wv_b  = (const float*)d_in[11];
    const float* ln_g  = (const float*)d_in[12];
    const float* ln_b  = (const float*)d_in[13];
    const float* ff1_w = (const float*)d_in[14];
    const float* ff1_b = (const float*)d_in[15];
    const float* ff2_w = (const float*)d_in[16];  // [512,49408]
    const float* ff2_b = (const float*)d_in[17];

    char* ws = (char*)d_ws;
    size_t o = 0;
    auto alloc = [&](size_t bytes) { size_t r = o; o += (bytes + 255) & ~(size_t)255; return r; };

    float*    x     = (float*)   (ws + alloc(4096ull * 512 * 4));
    ushort_t* xb    = (ushort_t*)(ws + alloc(4096ull * 512 * 2));
    float*    tmpf  = (float*)   (ws + alloc(4096ull * 512 * 4));   // img_out / attn / fftmp
    ushort_t* qkvb  = (ushort_t*)(ws + alloc(4096ull * 1536 * 2));  // [4096][q|k|v]
    float*    sc    = (float*)   (ws + alloc(32ull * 128 * 128 * 4));
    ushort_t* P     = (ushort_t*)(ws + alloc(32ull * 128 * 128 * 2));
    ushort_t* Atxt  = (ushort_t*)(ws + alloc(2560ull * 512 * 2));
    ushort_t* Aimg  = (ushort_t*)(ws + alloc(1664ull * 768 * 2));
    ushort_t* wqkvT = (ushort_t*)(ws + alloc(1536ull * 512 * 2));   // [wqT;wkT;wvT]
    ushort_t* ff0T  = (ushort_t*)(ws + alloc(512ull * 768 * 2));
    ushort_t* ff1T  = (ushort_t*)(ws + alloc(512ull * 512 * 2));
    float*    bcat  = (float*)   (ws + alloc(1536 * 4));
    size_t base_bytes = o;                                           // ~45 MB
    size_t ff2T_bytes = 49408ull * 512 * 2;                          // 50.6 MB
    bool use_ff2T = (ws_size >= base_bytes + ff2T_bytes + 256);
    ushort_t* ff2T = use_ff2T ? (ushort_t*)(ws + alloc(ff2T_bytes)) : nullptr;

    const float rsqd = 0.044194173824159216f; // 1/sqrt(512)
    const ushort_t* qb = qkvb;
    const ushort_t* kb = qkvb + 512;
    const ushort_t* vb = qkvb + 1024;
    dim3 b32x8(32, 8);

    transpose_bf<<<dim3(16, 16), b32x8, 0, stream>>>(wq, wqkvT, 512, 512);
    transpose_bf<<<dim3(16, 16), b32x8, 0, stream>>>(wk, wqkvT + 512 * 512, 512, 512);
    transpose_bf<<<dim3(16, 16), b32x8, 0, stream>>>(wv, wqkvT + 1024 * 512, 512, 512);
    transpose_bf<<<dim3(16, 24), b32x8, 0, stream>>>(ff0_w, ff0T, 768, 512);
    transpose_bf<<<dim3(16, 16), b32x8, 0, stream>>>(ff1_w, ff1T, 512, 512);
    biascat<<<6, 256, 0, stream>>>(wq_b, wk_b, wv_b, bcat);
    if (use_ff2T)
        transpose_bf<<<dim3(1544, 16), b32x8, 0, stream>>>(ff2_w, ff2T, 512, 49408);
    conv_pad<<<(1664 * 768 + 255) / 256, 256, 0, stream>>>(img, Aimg, 1600, 768, 1664 * 768);

    // ff0: img_out = Aimg @ ff0T^T + ff0_b -> tmpf [1600][512]
    gemm_bf16<0, 0><<<dim3(4, 13, 1), 256, 0, stream>>>(
        Aimg, ff0T, tmpf, nullptr, ff0_b, 768, 768, 768, 512, 0, 0, 0, 1600, 1.f);

    build_x<<<4096, 64, 0, stream>>>(tmpf, cap, tok, pos, ln_g, ln_b, x, xb);

    for (int l = 0; l < 2; l++) {
        // fused qkv: [4096][1536] = xb @ WqkvT^T + bcat   (wv_b included in V)
        gemm_bf16<0, 0><<<dim3(12, 32, 1), 256, 0, stream>>>(
            xb, wqkvT, nullptr, qkvb, bcat, 512, 512, 512, 1536, 0, 0, 0, 4096, 1.f);
        // scores[b] = q[b] @ k[b]^T / sqrt(512)
        gemm_bf16<0, 0><<<dim3(1, 1, 32), 256, 0, stream>>>(
            qb, kb, sc, nullptr, nullptr, 512, 1536, 1536, 128,
            (long)126 * 1536, (long)126 * 1536, (long)128 * 128, 128, rsqd);
        softmax_k<<<4096, 64, 0, stream>>>(sc, P);
        // attn[b] = P[b] @ V[b]   (V natural layout, BSRC=2; bias already in V)
        gemm_bf16<2, 0><<<dim3(4, 1, 32), 256, 0, stream>>>(
            P, vb, tmpf, nullptr, nullptr, 128, 128, 1536, 512,
            (long)128 * 128, (long)126 * 1536, (long)126 * 512, 126, 1.f);
        resln<<<4096, 64, 0, stream>>>(tmpf, ln_g, ln_b, x, xb);
        gemm_bf16<0, 0><<<dim3(4, 32, 1), 256, 0, stream>>>(
            xb, ff1T, tmpf, nullptr, ff1_b, 512, 512, 512, 512, 0, 0, 0, 4032, 1.f);
        resln<<<4096, 64, 0, stream>>>(tmpf, ln_g, ln_b, x, xb);
    }

    gather_txt<<<(2560 * 512 + 255) / 256, 256, 0, stream>>>(xb, Atxt);

    // logits (f32 out): d_out = Atxt @ ff2 + ff2_b, grouped-N(8) rasterization
    if (use_ff2T)
        gemm_bf16<0, 1><<<dim3(386, 20, 1), 256, 0, stream>>>(
            Atxt, ff2T, (float*)d_out, nullptr, ff2_b, 512, 512, 512, 49408,
            0, 0, 0, 2432, 1.f);
    else
        gemm_bf16<1, 1><<<dim3(386, 20, 1), 256, 0, stream>>>(
            Atxt, ff2_w, (float*)d_out, nullptr, ff2_b, 512, 512, 49408, 49408,
            0, 0, 0, 2432, 1.f);
}

// Round 9
// 540.273 us; speedup vs baseline: 7.0343x; 1.0680x over previous
//
#include <hip/hip_runtime.h>

typedef unsigned short ushort_t;
typedef __attribute__((ext_vector_type(8))) short short8;
typedef __attribute__((ext_vector_type(4))) float f32x4;
typedef __attribute__((ext_vector_type(4))) unsigned short bf4;
typedef __attribute__((ext_vector_type(8))) unsigned short bf8v;

__device__ __forceinline__ ushort_t f2bf(float f) {
    union { float f; unsigned u; } v; v.f = f;
    unsigned r = v.u + 0x7FFFu + ((v.u >> 16) & 1u);
    return (ushort_t)(r >> 16);
}

__device__ __forceinline__ void g2lds16(const ushort_t* g, ushort_t* l) {
    __builtin_amdgcn_global_load_lds(
        (const __attribute__((address_space(1))) void*)g,
        (__attribute__((address_space(3))) void*)l, 16, 0, 0);
}

#define LDT 72  // padded LDS row stride (reg-staged paths)

// ---------------------------------------------------------------------------
// Batched bf16 GEMM: C[m][n] = scale * sum_k A[m][k]*B'[n][k] + bias[n]
//   BSRC=0: B bf16 [N][ldb] rows (W^T). global_load_lds staging, linear LDS
//           with both-sides XOR swizzle (chunk ^= row&7): source-swizzled
//           gload (coalescing preserved within each 128B row segment) +
//           identically swizzled ds_read -> 16-way bank conflict -> 2-way.
//   BSRC=1: B f32  [K][ldb] natural W. reg-staged (fallback only).
//   BSRC=2: B bf16 [K][ldb] natural V. reg-staged.
// tile 128x128, BK=64, 4 waves (2x2), 16x16x32 MFMA.
// SWZ=1: grouped-N(8) rasterization for the logits GEMM.
// ---------------------------------------------------------------------------
template <int BSRC, int SWZ>
__global__ __launch_bounds__(256) void gemm_bf16(
    const ushort_t* __restrict__ A, const void* __restrict__ Bv,
    float* __restrict__ C, ushort_t* __restrict__ Cb,
    const float* __restrict__ bias,
    int K, int lda, int ldb, int ldc,
    long sA, long sB, long sC,
    int validM, float scale)
{
    constexpr int LS = (BSRC == 0) ? 64 : LDT;   // LDS row stride
    __shared__ __attribute__((aligned(16))) ushort_t As[128 * LS];
    __shared__ __attribute__((aligned(16))) ushort_t Bs[128 * LS];

    const int tid = threadIdx.x;
    const int lane = tid & 63;
    const int wave = tid >> 6;
    const int wr = wave >> 1, wc = wave & 1;
    int tN = blockIdx.x, tM = blockIdx.y;
    const int bz = blockIdx.z;
    if (SWZ) {
        const int lin = blockIdx.x + blockIdx.y * gridDim.x;
        const int TM = gridDim.y;
        const int full = gridDim.x >> 3;         // full groups of 8 columns
        const int per = TM << 3;                 // blocks per full group
        const int g = lin / per;
        if (g < full) {
            const int rem = lin - g * per;
            tM = rem >> 3;
            tN = (g << 3) + (rem & 7);
        } else {
            const int rem = lin - full * per;
            const int w = gridDim.x - (full << 3);
            tM = rem / w;
            tN = (full << 3) + rem - tM * w;
        }
    }
    const int n0 = tN * 128;

    const ushort_t* Abase = A + (long)bz * sA + (long)tM * 128 * lda;
    const ushort_t* Bb = (BSRC == 0)
        ? (const ushort_t*)Bv + (long)bz * sB + (long)n0 * ldb : nullptr;
    const float* Bf = (BSRC == 1)
        ? (const float*)Bv + (long)bz * sB : nullptr;
    const ushort_t* Bb2 = (BSRC == 2)
        ? (const ushort_t*)Bv + (long)bz * sB : nullptr;

    f32x4 acc[4][4];
#pragma unroll
    for (int m = 0; m < 4; m++)
#pragma unroll
        for (int n = 0; n < 4; n++) acc[m][n] = (f32x4)0.f;

    for (int ks = 0; ks < K; ks += 64) {
        if (BSRC == 0) {
            // -------- direct global->LDS staging, source-side swizzle ----
            if (ks) __syncthreads();             // readers of prev tile done
#pragma unroll
            for (int i = 0; i < 4; i++) {
                int ch = wave * 256 + i * 64 + lane;    // 16B chunk id
                int row = ch >> 3, c16 = ch & 7;
                int c16s = c16 ^ (row & 7);             // inverse swizzle
                g2lds16(Abase + (long)row * lda + ks + (c16s << 3),
                        As + (wave * 256 + i * 64) * 8);
            }
#pragma unroll
            for (int i = 0; i < 4; i++) {
                int ch = wave * 256 + i * 64 + lane;
                int row = ch >> 3, c16 = ch & 7;
                int c16s = c16 ^ (row & 7);
                g2lds16(Bb + (long)row * ldb + ks + (c16s << 3),
                        Bs + (wave * 256 + i * 64) * 8);
            }
            asm volatile("s_waitcnt vmcnt(0)" ::: "memory");
            __syncthreads();
        } else {
            // -------- reg-staged path (validated round-3/7 structure) ----
            short8 ar[4];
#pragma unroll
            for (int i = 0; i < 4; i++) {
                int ch = wave * 256 + i * 64 + lane;
                int row = ch >> 3, c16 = ch & 7;
                ar[i] = *(const short8*)(Abase + (long)row * lda + ks + (c16 << 3));
            }
            bf4 pk[8];
            if (BSRC == 1) {
#pragma unroll
                for (int q = 0; q < 8; q++) {
                    int qid = q * 256 + tid;
                    int n = qid & 127, kq = qid >> 7;
                    const float* wp = Bf + (long)(ks + kq * 4) * ldb + n0 + n;
                    bf4 p;
                    p[0] = f2bf(wp[0]);
                    p[1] = f2bf(wp[ldb]);
                    p[2] = f2bf(wp[2 * (long)ldb]);
                    p[3] = f2bf(wp[3 * (long)ldb]);
                    pk[q] = p;
                }
            } else {
#pragma unroll
                for (int q = 0; q < 8; q++) {
                    int qid = q * 256 + tid;
                    int n = qid & 127, kq = qid >> 7;
                    const ushort_t* wp = Bb2 + (long)(ks + kq * 4) * ldb + n0 + n;
                    bf4 p;
                    p[0] = wp[0];
                    p[1] = wp[ldb];
                    p[2] = wp[2 * (long)ldb];
                    p[3] = wp[3 * (long)ldb];
                    pk[q] = p;
                }
            }
            if (ks) __syncthreads();
#pragma unroll
            for (int i = 0; i < 4; i++) {
                int ch = wave * 256 + i * 64 + lane;
                int row = ch >> 3, c16 = ch & 7;
                *(short8*)(As + row * LS + (c16 << 3)) = ar[i];
            }
#pragma unroll
            for (int q = 0; q < 8; q++) {
                int qid = q * 256 + tid;
                int n = qid & 127, kq = qid >> 7;
                *(bf4*)(Bs + n * LS + (kq << 2)) = pk[q];
            }
            __syncthreads();
        }

        // ---- MFMA ----
#pragma unroll
        for (int ksub = 0; ksub < 2; ksub++) {
            const int kk = ksub * 32 + ((lane >> 4) << 3);
            const int kc = kk >> 3;                    // 16B chunk column
            short8 af[4], bfr[4];
#pragma unroll
            for (int m = 0; m < 4; m++) {
                const int r = (wr << 6) + m * 16 + (lane & 15);
                if (BSRC == 0)
                    af[m] = *(const short8*)(As + r * 64 + ((kc ^ (r & 7)) << 3));
                else
                    af[m] = *(const short8*)(As + r * LS + kk);
            }
#pragma unroll
            for (int n = 0; n < 4; n++) {
                const int r = (wc << 6) + n * 16 + (lane & 15);
                if (BSRC == 0)
                    bfr[n] = *(const short8*)(Bs + r * 64 + ((kc ^ (r & 7)) << 3));
                else
                    bfr[n] = *(const short8*)(Bs + r * LS + kk);
            }
#pragma unroll
            for (int m = 0; m < 4; m++)
#pragma unroll
                for (int n = 0; n < 4; n++)
                    acc[m][n] = __builtin_amdgcn_mfma_f32_16x16x32_bf16(
                        af[m], bfr[n], acc[m][n], 0, 0, 0);
        }
        if (BSRC != 0 && ks + 64 < K) __syncthreads();
    }

    const int rb = (wr << 6) + ((lane >> 4) << 2);
    const int cb = (wc << 6) + (lane & 15);
#pragma unroll
    for (int m = 0; m < 4; m++) {
#pragma unroll
        for (int i = 0; i < 4; i++) {
            int r = tM * 128 + rb + m * 16 + i;
            if (r >= validM) continue;
#pragma unroll
            for (int n = 0; n < 4; n++) {
                int cg = n0 + cb + n * 16;
                float v = acc[m][n][i] * scale + (bias ? bias[cg] : 0.f);
                long off = (long)bz * sC + (long)r * ldc + cg;
                if (C) C[off] = v;
                if (Cb) Cb[off] = f2bf(v);
            }
        }
    }
}

// ---------------------------------------------------------------------------
// transpose f32 [R][C] -> bf16 [C][R]
// ---------------------------------------------------------------------------
__global__ __launch_bounds__(256) void transpose_bf(
    const float* __restrict__ in, ushort_t* __restrict__ out, int R, int C)
{
    __shared__ float t[32][33];
    int c0 = blockIdx.x << 5, r0 = blockIdx.y << 5;
    int tx = threadIdx.x, ty = threadIdx.y;
#pragma unroll
    for (int i = 0; i < 4; i++)
        t[ty + i * 8][tx] = in[(long)(r0 + ty + i * 8) * C + c0 + tx];
    __syncthreads();
#pragma unroll
    for (int i = 0; i < 4; i++)
        out[(long)(c0 + ty + i * 8) * R + r0 + tx] = f2bf(t[tx][ty + i * 8]);
}

// concat 3 x [512] f32 bias vectors
__global__ __launch_bounds__(256) void biascat(
    const float* __restrict__ b0, const float* __restrict__ b1,
    const float* __restrict__ b2, float* __restrict__ out)
{
    int i = blockIdx.x * 256 + threadIdx.x;  // [0,1536)
    const float* s = (i < 512) ? b0 : (i < 1024) ? b1 : b2;
    out[i] = s[i & 511];
}

// f32 [validR][C] -> bf16 [Rpad][C] with zero pad
__global__ __launch_bounds__(256) void conv_pad(
    const float* __restrict__ in, ushort_t* __restrict__ out,
    int validR, int C, int total)
{
    int idx = blockIdx.x * 256 + threadIdx.x;
    if (idx >= total) return;
    int r = idx / C;
    float v = 0.f;
    if (r < validR) v = in[idx];
    out[idx] = f2bf(v);
}

// gather final-LN bf16 rows for txt positions -> Atxt [2560][512] (pad zero)
__global__ __launch_bounds__(256) void gather_txt(
    const ushort_t* __restrict__ xb, ushort_t* __restrict__ At)
{
    int idx = blockIdx.x * 256 + threadIdx.x;
    if (idx >= 2560 * 512) return;
    int r = idx >> 9, c = idx & 511;
    if (r < 2432) {
        int b = r / 76, t = r - b * 76;
        At[idx] = xb[((long)(b * 126 + 50 + t) << 9) + c];
    } else {
        At[idx] = 0;
    }
}

// build x = LN(concat(img_out, tok_emb[cap]+pos)) ; rows >= 4032 zeroed
__global__ __launch_bounds__(64) void build_x(
    const float* __restrict__ imgout, const int* __restrict__ cap,
    const float* __restrict__ tok, const float* __restrict__ pos,
    const float* __restrict__ g, const float* __restrict__ bb,
    float* __restrict__ x, ushort_t* __restrict__ xb)
{
    int r = blockIdx.x, lane = threadIdx.x;
    int c0 = lane << 3;
    long base = ((long)r << 9) + c0;
    if (r >= 4032) {
        *(f32x4*)(x + base) = (f32x4)0.f;
        *(f32x4*)(x + base + 4) = (f32x4)0.f;
        *(bf8v*)(xb + base) = (bf8v)0;
        return;
    }
    int b = r / 126, s = r - b * 126;
    float v[8];
    if (s < 50) {
        const float* src = imgout + ((long)(b * 50 + s) << 9) + c0;
        f32x4 a0 = *(const f32x4*)src, a1 = *(const f32x4*)(src + 4);
#pragma unroll
        for (int i = 0; i < 4; i++) { v[i] = a0[i]; v[4 + i] = a1[i]; }
    } else {
        int t = s - 50;
        int id = cap[b * 76 + t];
        const float* s1 = tok + ((long)id << 9) + c0;
        const float* s2 = pos + ((long)t << 9) + c0;
        f32x4 a0 = *(const f32x4*)s1, a1 = *(const f32x4*)(s1 + 4);
        f32x4 b0 = *(const f32x4*)s2, b1 = *(const f32x4*)(s2 + 4);
#pragma unroll
        for (int i = 0; i < 4; i++) { v[i] = a0[i] + b0[i]; v[4 + i] = a1[i] + b1[i]; }
    }
    float sum = 0.f, sq = 0.f;
#pragma unroll
    for (int i = 0; i < 8; i++) { sum += v[i]; sq += v[i] * v[i]; }
#pragma unroll
    for (int o = 32; o >= 1; o >>= 1) { sum += __shfl_xor(sum, o); sq += __shfl_xor(sq, o); }
    float mean = sum * (1.f / 512.f);
    float var = sq * (1.f / 512.f) - mean * mean;
    float inv = rsqrtf(var + 1e-5f);
    bf8v ob;
#pragma unroll
    for (int i = 0; i < 8; i++) {
        float y = (v[i] - mean) * inv * g[c0 + i] + bb[c0 + i];
        x[base + i] = y;
        ob[i] = f2bf(y);
    }
    *(bf8v*)(xb + base) = ob;
}

// x = LN(a + x) ; rows >= 4032 zeroed
__global__ __launch_bounds__(64) void resln(
    const float* __restrict__ a, const float* __restrict__ g,
    const float* __restrict__ bb, float* __restrict__ x, ushort_t* __restrict__ xb)
{
    int r = blockIdx.x, lane = threadIdx.x;
    int c0 = lane << 3;
    long base = ((long)r << 9) + c0;
    if (r >= 4032) {
        *(f32x4*)(x + base) = (f32x4)0.f;
        *(f32x4*)(x + base + 4) = (f32x4)0.f;
        *(bf8v*)(xb + base) = (bf8v)0;
        return;
    }
    f32x4 a0 = *(const f32x4*)(a + base), a1 = *(const f32x4*)(a + base + 4);
    f32x4 x0 = *(const f32x4*)(x + base), x1 = *(const f32x4*)(x + base + 4);
    float v[8];
#pragma unroll
    for (int i = 0; i < 4; i++) { v[i] = a0[i] + x0[i]; v[4 + i] = a1[i] + x1[i]; }
    float sum = 0.f, sq = 0.f;
#pragma unroll
    for (int i = 0; i < 8; i++) { sum += v[i]; sq += v[i] * v[i]; }
#pragma unroll
    for (int o = 32; o >= 1; o >>= 1) { sum += __shfl_xor(sum, o); sq += __shfl_xor(sq, o); }
    float mean = sum * (1.f / 512.f);
    float var = sq * (1.f / 512.f) - mean * mean;
    float inv = rsqrtf(var + 1e-5f);
    bf8v ob;
#pragma unroll
    for (int i = 0; i < 8; i++) {
        float y = (v[i] - mean) * inv * g[c0 + i] + bb[c0 + i];
        x[base + i] = y;
        ob[i] = f2bf(y);
    }
    *(bf8v*)(xb + base) = ob;
}

// scores [32][128][128] f32 -> P [32][128][128] bf16 with prefix-causal mask
__global__ __launch_bounds__(64) void softmax_k(
    const float* __restrict__ S, ushort_t* __restrict__ P)
{
    int bi = blockIdx.x;
    int row = bi & 127, b = bi >> 7;
    int lane = threadIdx.x;
    long base = (long)(b * 128 + row) << 7;
    if (row >= 126) { P[base + lane] = 0; P[base + lane + 64] = 0; return; }
    float v0 = S[base + lane], v1 = S[base + lane + 64];
    bool a0 = (lane < 50) || (lane <= row);        // j in [0,64)
    int j1 = lane + 64;
    bool a1 = (j1 < 126) && (j1 <= row);           // j in [64,128)
    float m = fmaxf(a0 ? v0 : -3e38f, a1 ? v1 : -3e38f);
#pragma unroll
    for (int o = 32; o >= 1; o >>= 1) m = fmaxf(m, __shfl_xor(m, o));
    float e0 = a0 ? expf(v0 - m) : 0.f;
    float e1 = a1 ? expf(v1 - m) : 0.f;
    float s = e0 + e1;
#pragma unroll
    for (int o = 32; o >= 1; o >>= 1) s += __shfl_xor(s, o);
    float inv = 1.f / s;
    P[base + lane] = f2bf(e0 * inv);
    P[base + lane + 64] = f2bf(e1 * inv);
}

// ---------------------------------------------------------------------------
extern "C" void kernel_launch(void* const* d_in, const int* in_sizes, int n_in,
                              void* d_out, int out_size, void* d_ws, size_t ws_size,
                              hipStream_t stream)
{
    const float* img   = (const float*)d_in[0];   // [32,50,768]
    const int*   cap   = (const int*)  d_in[1];   // [32,76]
    const float* tok   = (const float*)d_in[2];   // [49408,512]
    const float* pos   = (const float*)d_in[3];   // [76,512]
    const float* ff0_w = (const float*)d_in[4];   // [768,512]
    const float* ff0_b = (const float*)d_in[5];
    const float* wq    = (const float*)d_in[6];
    const float* wq_b  = (const float*)d_in[7];
    const float* wk    = (const float*)d_in[8];
    const float* wk_b  = (const float*)d_in[9];
    const float* wv    = (const float*)d_in[10];
    const float* wv_b  = (const float*)d_in[11];
    const float* ln_g  = (const float*)d_in[12];
    const float* ln_b  = (const float*)d_in[13];
    const float* ff1_w = (const float*)d_in[14];
    const float* ff1_b = (const float*)d_in[15];
    const float* ff2_w = (const float*)d_in[16];  // [512,49408]
    const float* ff2_b = (const float*)d_in[17];

    char* ws = (char*)d_ws;
    size_t o = 0;
    auto alloc = [&](size_t bytes) { size_t r = o; o += (bytes + 255) & ~(size_t)255; return r; };

    float*    x     = (float*)   (ws + alloc(4096ull * 512 * 4));
    ushort_t* xb    = (ushort_t*)(ws + alloc(4096ull * 512 * 2));
    float*    tmpf  = (float*)   (ws + alloc(4096ull * 512 * 4));   // img_out / attn / fftmp
    ushort_t* qkvb  = (ushort_t*)(ws + alloc(4096ull * 1536 * 2));  // [4096][q|k|v]
    float*    sc    = (float*)   (ws + alloc(32ull * 128 * 128 * 4));
    ushort_t* P     = (ushort_t*)(ws + alloc(32ull * 128 * 128 * 2));
    ushort_t* Atxt  = (ushort_t*)(ws + alloc(2560ull * 512 * 2));
    ushort_t* Aimg  = (ushort_t*)(ws + alloc(1664ull * 768 * 2));
    ushort_t* wqkvT = (ushort_t*)(ws + alloc(1536ull * 512 * 2));   // [wqT;wkT;wvT]
    ushort_t* ff0T  = (ushort_t*)(ws + alloc(512ull * 768 * 2));
    ushort_t* ff1T  = (ushort_t*)(ws + alloc(512ull * 512 * 2));
    float*    bcat  = (float*)   (ws + alloc(1536 * 4));
    size_t base_bytes = o;                                           // ~45 MB
    size_t ff2T_bytes = 49408ull * 512 * 2;                          // 50.6 MB
    bool use_ff2T = (ws_size >= base_bytes + ff2T_bytes + 256);
    ushort_t* ff2T = use_ff2T ? (ushort_t*)(ws + alloc(ff2T_bytes)) : nullptr;

    const float rsqd = 0.044194173824159216f; // 1/sqrt(512)
    const ushort_t* qb = qkvb;
    const ushort_t* kb = qkvb + 512;
    const ushort_t* vb = qkvb + 1024;
    dim3 b32x8(32, 8);

    transpose_bf<<<dim3(16, 16), b32x8, 0, stream>>>(wq, wqkvT, 512, 512);
    transpose_bf<<<dim3(16, 16), b32x8, 0, stream>>>(wk, wqkvT + 512 * 512, 512, 512);
    transpose_bf<<<dim3(16, 16), b32x8, 0, stream>>>(wv, wqkvT + 1024 * 512, 512, 512);
    transpose_bf<<<dim3(16, 24), b32x8, 0, stream>>>(ff0_w, ff0T, 768, 512);
    transpose_bf<<<dim3(16, 16), b32x8, 0, stream>>>(ff1_w, ff1T, 512, 512);
    biascat<<<6, 256, 0, stream>>>(wq_b, wk_b, wv_b, bcat);
    if (use_ff2T)
        transpose_bf<<<dim3(1544, 16), b32x8, 0, stream>>>(ff2_w, ff2T, 512, 49408);
    conv_pad<<<(1664 * 768 + 255) / 256, 256, 0, stream>>>(img, Aimg, 1600, 768, 1664 * 768);

    // ff0: img_out = Aimg @ ff0T^T + ff0_b -> tmpf [1600][512]
    gemm_bf16<0, 0><<<dim3(4, 13, 1), 256, 0, stream>>>(
        Aimg, ff0T, tmpf, nullptr, ff0_b, 768, 768, 768, 512, 0, 0, 0, 1600, 1.f);

    build_x<<<4096, 64, 0, stream>>>(tmpf, cap, tok, pos, ln_g, ln_b, x, xb);

    for (int l = 0; l < 2; l++) {
        // fused qkv: [4096][1536] = xb @ WqkvT^T + bcat   (wv_b included in V)
        gemm_bf16<0, 0><<<dim3(12, 32, 1), 256, 0, stream>>>(
            xb, wqkvT, nullptr, qkvb, bcat, 512, 512, 512, 1536, 0, 0, 0, 4096, 1.f);
        // scores[b] = q[b] @ k[b]^T / sqrt(512)
        gemm_bf16<0, 0><<<dim3(1, 1, 32), 256, 0, stream>>>(
            qb, kb, sc, nullptr, nullptr, 512, 1536, 1536, 128,
            (long)126 * 1536, (long)126 * 1536, (long)128 * 128, 128, rsqd);
        softmax_k<<<4096, 64, 0, stream>>>(sc, P);
        // attn[b] = P[b] @ V[b]   (V natural layout, BSRC=2; bias already in V)
        gemm_bf16<2, 0><<<dim3(4, 1, 32), 256, 0, stream>>>(
            P, vb, tmpf, nullptr, nullptr, 128, 128, 1536, 512,
            (long)128 * 128, (long)126 * 1536, (long)126 * 512, 126, 1.f);
        resln<<<4096, 64, 0, stream>>>(tmpf, ln_g, ln_b, x, xb);
        gemm_bf16<0, 0><<<dim3(4, 32, 1), 256, 0, stream>>>(
            xb, ff1T, tmpf, nullptr, ff1_b, 512, 512, 512, 512, 0, 0, 0, 4032, 1.f);
        resln<<<4096, 64, 0, stream>>>(tmpf, ln_g, ln_b, x, xb);
    }

    gather_txt<<<(2560 * 512 + 255) / 256, 256, 0, stream>>>(xb, Atxt);

    // logits (f32 out): d_out = Atxt @ ff2 + ff2_b, grouped-N(8) rasterization
    if (use_ff2T)
        gemm_bf16<0, 1><<<dim3(386, 20, 1), 256, 0, stream>>>(
            Atxt, ff2T, (float*)d_out, nullptr, ff2_b, 512, 512, 512, 49408,
            0, 0, 0, 2432, 1.f);
    else
        gemm_bf16<1, 1><<<dim3(386, 20, 1), 256, 0, stream>>>(
            Atxt, ff2_w, (float*)d_out, nullptr, ff2_b, 512, 512, 49408, 49408,
            0, 0, 0, 2432, 1.f);
}

// Round 10
// 516.702 us; speedup vs baseline: 7.3552x; 1.0456x over previous
//
#include <hip/hip_runtime.h>

typedef unsigned short ushort_t;
typedef __attribute__((ext_vector_type(8))) short short8;
typedef __attribute__((ext_vector_type(4))) float f32x4;
typedef __attribute__((ext_vector_type(4))) unsigned short bf4;
typedef __attribute__((ext_vector_type(8))) unsigned short bf8v;

__device__ __forceinline__ ushort_t f2bf(float f) {
    union { float f; unsigned u; } v; v.f = f;
    unsigned r = v.u + 0x7FFFu + ((v.u >> 16) & 1u);
    return (ushort_t)(r >> 16);
}

__device__ __forceinline__ void g2lds16(const ushort_t* g, ushort_t* l) {
    __builtin_amdgcn_global_load_lds(
        (const __attribute__((address_space(1))) void*)g,
        (__attribute__((address_space(3))) void*)l, 16, 0, 0);
}

#define LDT 72  // padded LDS row stride (reg-staged paths)

// ---------------------------------------------------------------------------
// Batched bf16 GEMM: C[m][n] = scale * sum_k A[m][k]*B'[n][k] + bias[n]
//   BSRC=0: B bf16 [N][ldb] rows (W^T). global_load_lds + double-buffered
//           counted-vmcnt pipeline (T3/T4 minimum form): issue next tile's
//           loads, s_waitcnt vmcnt(8) (drains only the OLDEST 8 = current
//           tile), raw asm s_barrier (avoids __syncthreads' implicit
//           vmcnt(0) drain). XOR swizzle on source+read (round-9, conflicts=0).
//   BSRC=1: B f32  [K][ldb] natural W. reg-staged (fallback only).
//   BSRC=2: B bf16 [K][ldb] natural V. reg-staged.
// tile 128x128, BK=64, 4 waves (2x2), 16x16x32 MFMA.
// SWZ=1: grouped-N(8) rasterization. NT=1: nontemporal C stores (logits).
// ---------------------------------------------------------------------------
template <int BSRC, int SWZ, int NT>
__global__ __launch_bounds__(256) void gemm_bf16(
    const ushort_t* __restrict__ A, const void* __restrict__ Bv,
    float* __restrict__ C, ushort_t* __restrict__ Cb,
    const float* __restrict__ bias,
    int K, int lda, int ldb, int ldc,
    long sA, long sB, long sC,
    int validM, float scale)
{
    constexpr int LS = (BSRC == 0) ? 64 : LDT;   // LDS row stride
    constexpr int NBUF = (BSRC == 0) ? 2 : 1;
    __shared__ __attribute__((aligned(16))) ushort_t As[NBUF * 128 * LS];
    __shared__ __attribute__((aligned(16))) ushort_t Bs[NBUF * 128 * LS];

    const int tid = threadIdx.x;
    const int lane = tid & 63;
    const int wave = tid >> 6;
    const int wr = wave >> 1, wc = wave & 1;
    int tN = blockIdx.x, tM = blockIdx.y;
    const int bz = blockIdx.z;
    if (SWZ) {
        const int lin = blockIdx.x + blockIdx.y * gridDim.x;
        const int TM = gridDim.y;
        const int full = gridDim.x >> 3;         // full groups of 8 columns
        const int per = TM << 3;                 // blocks per full group
        const int g = lin / per;
        if (g < full) {
            const int rem = lin - g * per;
            tM = rem >> 3;
            tN = (g << 3) + (rem & 7);
        } else {
            const int rem = lin - full * per;
            const int w = gridDim.x - (full << 3);
            tM = rem / w;
            tN = (full << 3) + rem - tM * w;
        }
    }
    const int n0 = tN * 128;

    const ushort_t* Abase = A + (long)bz * sA + (long)tM * 128 * lda;
    const ushort_t* Bb = (BSRC == 0)
        ? (const ushort_t*)Bv + (long)bz * sB + (long)n0 * ldb : nullptr;
    const float* Bf = (BSRC == 1)
        ? (const float*)Bv + (long)bz * sB : nullptr;
    const ushort_t* Bb2 = (BSRC == 2)
        ? (const ushort_t*)Bv + (long)bz * sB : nullptr;

    f32x4 acc[4][4];
#pragma unroll
    for (int m = 0; m < 4; m++)
#pragma unroll
        for (int n = 0; n < 4; n++) acc[m][n] = (f32x4)0.f;

    if (BSRC == 0) {
        // ================= pipelined global_load_lds path =================
        auto STAGE = [&](int buf, int ks) {
            ushort_t* Ad = As + buf * (128 * 64);
            ushort_t* Bd = Bs + buf * (128 * 64);
#pragma unroll
            for (int i = 0; i < 4; i++) {
                int ch = wave * 256 + i * 64 + lane;    // 16B chunk id
                int row = ch >> 3, c16 = ch & 7;
                int c16s = c16 ^ (row & 7);             // inverse swizzle
                g2lds16(Abase + (long)row * lda + ks + (c16s << 3),
                        Ad + (wave * 256 + i * 64) * 8);
            }
#pragma unroll
            for (int i = 0; i < 4; i++) {
                int ch = wave * 256 + i * 64 + lane;
                int row = ch >> 3, c16 = ch & 7;
                int c16s = c16 ^ (row & 7);
                g2lds16(Bb + (long)row * ldb + ks + (c16s << 3),
                        Bd + (wave * 256 + i * 64) * 8);
            }
        };

        const int nt = K >> 6;
        STAGE(0, 0);                               // prologue
        for (int t = 0; t < nt; ++t) {
            if (t + 1 < nt) {
                STAGE((t + 1) & 1, (t + 1) << 6);  // issue next tile first
                asm volatile("s_waitcnt vmcnt(8)" ::: "memory");  // drain cur
            } else {
                asm volatile("s_waitcnt vmcnt(0)" ::: "memory");
            }
            asm volatile("s_barrier" ::: "memory");

            const ushort_t* Ac = As + (t & 1) * (128 * 64);
            const ushort_t* Bc = Bs + (t & 1) * (128 * 64);
#pragma unroll
            for (int ksub = 0; ksub < 2; ksub++) {
                const int kk = ksub * 32 + ((lane >> 4) << 3);
                const int kc = kk >> 3;                // 16B chunk column
                short8 af[4], bfr[4];
#pragma unroll
                for (int m = 0; m < 4; m++) {
                    const int r = (wr << 6) + m * 16 + (lane & 15);
                    af[m] = *(const short8*)(Ac + r * 64 + ((kc ^ (r & 7)) << 3));
                }
#pragma unroll
                for (int n = 0; n < 4; n++) {
                    const int r = (wc << 6) + n * 16 + (lane & 15);
                    bfr[n] = *(const short8*)(Bc + r * 64 + ((kc ^ (r & 7)) << 3));
                }
#pragma unroll
                for (int m = 0; m < 4; m++)
#pragma unroll
                    for (int n = 0; n < 4; n++)
                        acc[m][n] = __builtin_amdgcn_mfma_f32_16x16x32_bf16(
                            af[m], bfr[n], acc[m][n], 0, 0, 0);
            }
            asm volatile("s_barrier" ::: "memory"); // readers done -> next stage may overwrite
        }
    } else {
        // ================= reg-staged path (validated) ====================
        for (int ks = 0; ks < K; ks += 64) {
            short8 ar[4];
#pragma unroll
            for (int i = 0; i < 4; i++) {
                int ch = wave * 256 + i * 64 + lane;
                int row = ch >> 3, c16 = ch & 7;
                ar[i] = *(const short8*)(Abase + (long)row * lda + ks + (c16 << 3));
            }
            bf4 pk[8];
            if (BSRC == 1) {
#pragma unroll
                for (int q = 0; q < 8; q++) {
                    int qid = q * 256 + tid;
                    int n = qid & 127, kq = qid >> 7;
                    const float* wp = Bf + (long)(ks + kq * 4) * ldb + n0 + n;
                    bf4 p;
                    p[0] = f2bf(wp[0]);
                    p[1] = f2bf(wp[ldb]);
                    p[2] = f2bf(wp[2 * (long)ldb]);
                    p[3] = f2bf(wp[3 * (long)ldb]);
                    pk[q] = p;
                }
            } else {
#pragma unroll
                for (int q = 0; q < 8; q++) {
                    int qid = q * 256 + tid;
                    int n = qid & 127, kq = qid >> 7;
                    const ushort_t* wp = Bb2 + (long)(ks + kq * 4) * ldb + n0 + n;
                    bf4 p;
                    p[0] = wp[0];
                    p[1] = wp[ldb];
                    p[2] = wp[2 * (long)ldb];
                    p[3] = wp[3 * (long)ldb];
                    pk[q] = p;
                }
            }
            if (ks) __syncthreads();
#pragma unroll
            for (int i = 0; i < 4; i++) {
                int ch = wave * 256 + i * 64 + lane;
                int row = ch >> 3, c16 = ch & 7;
                *(short8*)(As + row * LS + (c16 << 3)) = ar[i];
            }
#pragma unroll
            for (int q = 0; q < 8; q++) {
                int qid = q * 256 + tid;
                int n = qid & 127, kq = qid >> 7;
                *(bf4*)(Bs + n * LS + (kq << 2)) = pk[q];
            }
            __syncthreads();

#pragma unroll
            for (int ksub = 0; ksub < 2; ksub++) {
                const int kk = ksub * 32 + ((lane >> 4) << 3);
                short8 af[4], bfr[4];
#pragma unroll
                for (int m = 0; m < 4; m++) {
                    const int r = (wr << 6) + m * 16 + (lane & 15);
                    af[m] = *(const short8*)(As + r * LS + kk);
                }
#pragma unroll
                for (int n = 0; n < 4; n++) {
                    const int r = (wc << 6) + n * 16 + (lane & 15);
                    bfr[n] = *(const short8*)(Bs + r * LS + kk);
                }
#pragma unroll
                for (int m = 0; m < 4; m++)
#pragma unroll
                    for (int n = 0; n < 4; n++)
                        acc[m][n] = __builtin_amdgcn_mfma_f32_16x16x32_bf16(
                            af[m], bfr[n], acc[m][n], 0, 0, 0);
            }
            if (ks + 64 < K) __syncthreads();
        }
    }

    const int rb = (wr << 6) + ((lane >> 4) << 2);
    const int cb = (wc << 6) + (lane & 15);
#pragma unroll
    for (int m = 0; m < 4; m++) {
#pragma unroll
        for (int i = 0; i < 4; i++) {
            int r = tM * 128 + rb + m * 16 + i;
            if (r >= validM) continue;
#pragma unroll
            for (int n = 0; n < 4; n++) {
                int cg = n0 + cb + n * 16;
                float v = acc[m][n][i] * scale + (bias ? bias[cg] : 0.f);
                long off = (long)bz * sC + (long)r * ldc + cg;
                if (C) {
                    if (NT) __builtin_nontemporal_store(v, &C[off]);
                    else    C[off] = v;
                }
                if (Cb) Cb[off] = f2bf(v);
            }
        }
    }
}

// ---------------------------------------------------------------------------
// transpose f32 [R][C] -> bf16 [C][R]
// ---------------------------------------------------------------------------
__global__ __launch_bounds__(256) void transpose_bf(
    const float* __restrict__ in, ushort_t* __restrict__ out, int R, int C)
{
    __shared__ float t[32][33];
    int c0 = blockIdx.x << 5, r0 = blockIdx.y << 5;
    int tx = threadIdx.x, ty = threadIdx.y;
#pragma unroll
    for (int i = 0; i < 4; i++)
        t[ty + i * 8][tx] = in[(long)(r0 + ty + i * 8) * C + c0 + tx];
    __syncthreads();
#pragma unroll
    for (int i = 0; i < 4; i++)
        out[(long)(c0 + ty + i * 8) * R + r0 + tx] = f2bf(t[tx][ty + i * 8]);
}

// concat 3 x [512] f32 bias vectors
__global__ __launch_bounds__(256) void biascat(
    const float* __restrict__ b0, const float* __restrict__ b1,
    const float* __restrict__ b2, float* __restrict__ out)
{
    int i = blockIdx.x * 256 + threadIdx.x;  // [0,1536)
    const float* s = (i < 512) ? b0 : (i < 1024) ? b1 : b2;
    out[i] = s[i & 511];
}

// f32 [validR][C] -> bf16 [Rpad][C] with zero pad
__global__ __launch_bounds__(256) void conv_pad(
    const float* __restrict__ in, ushort_t* __restrict__ out,
    int validR, int C, int total)
{
    int idx = blockIdx.x * 256 + threadIdx.x;
    if (idx >= total) return;
    int r = idx / C;
    float v = 0.f;
    if (r < validR) v = in[idx];
    out[idx] = f2bf(v);
}

// gather final-LN bf16 rows for txt positions -> Atxt [2560][512] (pad zero)
__global__ __launch_bounds__(256) void gather_txt(
    const ushort_t* __restrict__ xb, ushort_t* __restrict__ At)
{
    int idx = blockIdx.x * 256 + threadIdx.x;
    if (idx >= 2560 * 512) return;
    int r = idx >> 9, c = idx & 511;
    if (r < 2432) {
        int b = r / 76, t = r - b * 76;
        At[idx] = xb[((long)(b * 126 + 50 + t) << 9) + c];
    } else {
        At[idx] = 0;
    }
}

// build x = LN(concat(img_out, tok_emb[cap]+pos)) ; rows >= 4032 zeroed
__global__ __launch_bounds__(64) void build_x(
    const float* __restrict__ imgout, const int* __restrict__ cap,
    const float* __restrict__ tok, const float* __restrict__ pos,
    const float* __restrict__ g, const float* __restrict__ bb,
    float* __restrict__ x, ushort_t* __restrict__ xb)
{
    int r = blockIdx.x, lane = threadIdx.x;
    int c0 = lane << 3;
    long base = ((long)r << 9) + c0;
    if (r >= 4032) {
        *(f32x4*)(x + base) = (f32x4)0.f;
        *(f32x4*)(x + base + 4) = (f32x4)0.f;
        *(bf8v*)(xb + base) = (bf8v)0;
        return;
    }
    int b = r / 126, s = r - b * 126;
    float v[8];
    if (s < 50) {
        const float* src = imgout + ((long)(b * 50 + s) << 9) + c0;
        f32x4 a0 = *(const f32x4*)src, a1 = *(const f32x4*)(src + 4);
#pragma unroll
        for (int i = 0; i < 4; i++) { v[i] = a0[i]; v[4 + i] = a1[i]; }
    } else {
        int t = s - 50;
        int id = cap[b * 76 + t];
        const float* s1 = tok + ((long)id << 9) + c0;
        const float* s2 = pos + ((long)t << 9) + c0;
        f32x4 a0 = *(const f32x4*)s1, a1 = *(const f32x4*)(s1 + 4);
        f32x4 b0 = *(const f32x4*)s2, b1 = *(const f32x4*)(s2 + 4);
#pragma unroll
        for (int i = 0; i < 4; i++) { v[i] = a0[i] + b0[i]; v[4 + i] = a1[i] + b1[i]; }
    }
    float sum = 0.f, sq = 0.f;
#pragma unroll
    for (int i = 0; i < 8; i++) { sum += v[i]; sq += v[i] * v[i]; }
#pragma unroll
    for (int o = 32; o >= 1; o >>= 1) { sum += __shfl_xor(sum, o); sq += __shfl_xor(sq, o); }
    float mean = sum * (1.f / 512.f);
    float var = sq * (1.f / 512.f) - mean * mean;
    float inv = rsqrtf(var + 1e-5f);
    bf8v ob;
#pragma unroll
    for (int i = 0; i < 8; i++) {
        float y = (v[i] - mean) * inv * g[c0 + i] + bb[c0 + i];
        x[base + i] = y;
        ob[i] = f2bf(y);
    }
    *(bf8v*)(xb + base) = ob;
}

// x = LN(a + x) ; rows >= 4032 zeroed
__global__ __launch_bounds__(64) void resln(
    const float* __restrict__ a, const float* __restrict__ g,
    const float* __restrict__ bb, float* __restrict__ x, ushort_t* __restrict__ xb)
{
    int r = blockIdx.x, lane = threadIdx.x;
    int c0 = lane << 3;
    long base = ((long)r << 9) + c0;
    if (r >= 4032) {
        *(f32x4*)(x + base) = (f32x4)0.f;
        *(f32x4*)(x + base + 4) = (f32x4)0.f;
        *(bf8v*)(xb + base) = (bf8v)0;
        return;
    }
    f32x4 a0 = *(const f32x4*)(a + base), a1 = *(const f32x4*)(a + base + 4);
    f32x4 x0 = *(const f32x4*)(x + base), x1 = *(const f32x4*)(x + base + 4);
    float v[8];
#pragma unroll
    for (int i = 0; i < 4; i++) { v[i] = a0[i] + x0[i]; v[4 + i] = a1[i] + x1[i]; }
    float sum = 0.f, sq = 0.f;
#pragma unroll
    for (int i = 0; i < 8; i++) { sum += v[i]; sq += v[i] * v[i]; }
#pragma unroll
    for (int o = 32; o >= 1; o >>= 1) { sum += __shfl_xor(sum, o); sq += __shfl_xor(sq, o); }
    float mean = sum * (1.f / 512.f);
    float var = sq * (1.f / 512.f) - mean * mean;
    float inv = rsqrtf(var + 1e-5f);
    bf8v ob;
#pragma unroll
    for (int i = 0; i < 8; i++) {
        float y = (v[i] - mean) * inv * g[c0 + i] + bb[c0 + i];
        x[base + i] = y;
        ob[i] = f2bf(y);
    }
    *(bf8v*)(xb + base) = ob;
}

// scores [32][128][128] f32 -> P [32][128][128] bf16 with prefix-causal mask
__global__ __launch_bounds__(64) void softmax_k(
    const float* __restrict__ S, ushort_t* __restrict__ P)
{
    int bi = blockIdx.x;
    int row = bi & 127, b = bi >> 7;
    int lane = threadIdx.x;
    long base = (long)(b * 128 + row) << 7;
    if (row >= 126) { P[base + lane] = 0; P[base + lane + 64] = 0; return; }
    float v0 = S[base + lane], v1 = S[base + lane + 64];
    bool a0 = (lane < 50) || (lane <= row);        // j in [0,64)
    int j1 = lane + 64;
    bool a1 = (j1 < 126) && (j1 <= row);           // j in [64,128)
    float m = fmaxf(a0 ? v0 : -3e38f, a1 ? v1 : -3e38f);
#pragma unroll
    for (int o = 32; o >= 1; o >>= 1) m = fmaxf(m, __shfl_xor(m, o));
    float e0 = a0 ? expf(v0 - m) : 0.f;
    float e1 = a1 ? expf(v1 - m) : 0.f;
    float s = e0 + e1;
#pragma unroll
    for (int o = 32; o >= 1; o >>= 1) s += __shfl_xor(s, o);
    float inv = 1.f / s;
    P[base + lane] = f2bf(e0 * inv);
    P[base + lane + 64] = f2bf(e1 * inv);
}

// ---------------------------------------------------------------------------
extern "C" void kernel_launch(void* const* d_in, const int* in_sizes, int n_in,
                              void* d_out, int out_size, void* d_ws, size_t ws_size,
                              hipStream_t stream)
{
    const float* img   = (const float*)d_in[0];   // [32,50,768]
    const int*   cap   = (const int*)  d_in[1];   // [32,76]
    const float* tok   = (const float*)d_in[2];   // [49408,512]
    const float* pos   = (const float*)d_in[3];   // [76,512]
    const float* ff0_w = (const float*)d_in[4];   // [768,512]
    const float* ff0_b = (const float*)d_in[5];
    const float* wq    = (const float*)d_in[6];
    const float* wq_b  = (const float*)d_in[7];
    const float* wk    = (const float*)d_in[8];
    const float* wk_b  = (const float*)d_in[9];
    const float* wv    = (const float*)d_in[10];
    const float* wv_b  = (const float*)d_in[11];
    const float* ln_g  = (const float*)d_in[12];
    const float* ln_b  = (const float*)d_in[13];
    const float* ff1_w = (const float*)d_in[14];
    const float* ff1_b = (const float*)d_in[15];
    const float* ff2_w = (const float*)d_in[16];  // [512,49408]
    const float* ff2_b = (const float*)d_in[17];

    char* ws = (char*)d_ws;
    size_t o = 0;
    auto alloc = [&](size_t bytes) { size_t r = o; o += (bytes + 255) & ~(size_t)255; return r; };

    float*    x     = (float*)   (ws + alloc(4096ull * 512 * 4));
    ushort_t* xb    = (ushort_t*)(ws + alloc(4096ull * 512 * 2));
    float*    tmpf  = (float*)   (ws + alloc(4096ull * 512 * 4));   // img_out / attn / fftmp
    ushort_t* qkvb  = (ushort_t*)(ws + alloc(4096ull * 1536 * 2));  // [4096][q|k|v]
    float*    sc    = (float*)   (ws + alloc(32ull * 128 * 128 * 4));
    ushort_t* P     = (ushort_t*)(ws + alloc(32ull * 128 * 128 * 2));
    ushort_t* Atxt  = (ushort_t*)(ws + alloc(2560ull * 512 * 2));
    ushort_t* Aimg  = (ushort_t*)(ws + alloc(1664ull * 768 * 2));
    ushort_t* wqkvT = (ushort_t*)(ws + alloc(1536ull * 512 * 2));   // [wqT;wkT;wvT]
    ushort_t* ff0T  = (ushort_t*)(ws + alloc(512ull * 768 * 2));
    ushort_t* ff1T  = (ushort_t*)(ws + alloc(512ull * 512 * 2));
    float*    bcat  = (float*)   (ws + alloc(1536 * 4));
    size_t base_bytes = o;                                           // ~45 MB
    size_t ff2T_bytes = 49408ull * 512 * 2;                          // 50.6 MB
    bool use_ff2T = (ws_size >= base_bytes + ff2T_bytes + 256);
    ushort_t* ff2T = use_ff2T ? (ushort_t*)(ws + alloc(ff2T_bytes)) : nullptr;

    const float rsqd = 0.044194173824159216f; // 1/sqrt(512)
    const ushort_t* qb = qkvb;
    const ushort_t* kb = qkvb + 512;
    const ushort_t* vb = qkvb + 1024;
    dim3 b32x8(32, 8);

    transpose_bf<<<dim3(16, 16), b32x8, 0, stream>>>(wq, wqkvT, 512, 512);
    transpose_bf<<<dim3(16, 16), b32x8, 0, stream>>>(wk, wqkvT + 512 * 512, 512, 512);
    transpose_bf<<<dim3(16, 16), b32x8, 0, stream>>>(wv, wqkvT + 1024 * 512, 512, 512);
    transpose_bf<<<dim3(16, 24), b32x8, 0, stream>>>(ff0_w, ff0T, 768, 512);
    transpose_bf<<<dim3(16, 16), b32x8, 0, stream>>>(ff1_w, ff1T, 512, 512);
    biascat<<<6, 256, 0, stream>>>(wq_b, wk_b, wv_b, bcat);
    if (use_ff2T)
        transpose_bf<<<dim3(1544, 16), b32x8, 0, stream>>>(ff2_w, ff2T, 512, 49408);
    conv_pad<<<(1664 * 768 + 255) / 256, 256, 0, stream>>>(img, Aimg, 1600, 768, 1664 * 768);

    // ff0: img_out = Aimg @ ff0T^T + ff0_b -> tmpf [1600][512]
    gemm_bf16<0, 0, 0><<<dim3(4, 13, 1), 256, 0, stream>>>(
        Aimg, ff0T, tmpf, nullptr, ff0_b, 768, 768, 768, 512, 0, 0, 0, 1600, 1.f);

    build_x<<<4096, 64, 0, stream>>>(tmpf, cap, tok, pos, ln_g, ln_b, x, xb);

    for (int l = 0; l < 2; l++) {
        // fused qkv: [4096][1536] = xb @ WqkvT^T + bcat   (wv_b included in V)
        gemm_bf16<0, 0, 0><<<dim3(12, 32, 1), 256, 0, stream>>>(
            xb, wqkvT, nullptr, qkvb, bcat, 512, 512, 512, 1536, 0, 0, 0, 4096, 1.f);
        // scores[b] = q[b] @ k[b]^T / sqrt(512)
        gemm_bf16<0, 0, 0><<<dim3(1, 1, 32), 256, 0, stream>>>(
            qb, kb, sc, nullptr, nullptr, 512, 1536, 1536, 128,
            (long)126 * 1536, (long)126 * 1536, (long)128 * 128, 128, rsqd);
        softmax_k<<<4096, 64, 0, stream>>>(sc, P);
        // attn[b] = P[b] @ V[b]   (V natural layout, BSRC=2; bias already in V)
        gemm_bf16<2, 0, 0><<<dim3(4, 1, 32), 256, 0, stream>>>(
            P, vb, tmpf, nullptr, nullptr, 128, 128, 1536, 512,
            (long)128 * 128, (long)126 * 1536, (long)126 * 512, 126, 1.f);
        resln<<<4096, 64, 0, stream>>>(tmpf, ln_g, ln_b, x, xb);
        gemm_bf16<0, 0, 0><<<dim3(4, 32, 1), 256, 0, stream>>>(
            xb, ff1T, tmpf, nullptr, ff1_b, 512, 512, 512, 512, 0, 0, 0, 4032, 1.f);
        resln<<<4096, 64, 0, stream>>>(tmpf, ln_g, ln_b, x, xb);
    }

    gather_txt<<<(2560 * 512 + 255) / 256, 256, 0, stream>>>(xb, Atxt);

    // logits (f32 out): d_out = Atxt @ ff2 + ff2_b, grouped-N(8), NT stores
    if (use_ff2T)
        gemm_bf16<0, 1, 1><<<dim3(386, 20, 1), 256, 0, stream>>>(
            Atxt, ff2T, (float*)d_out, nullptr, ff2_b, 512, 512, 512, 49408,
            0, 0, 0, 2432, 1.f);
    else
        gemm_bf16<1, 1, 1><<<dim3(386, 20, 1), 256, 0, stream>>>(
            Atxt, ff2_w, (float*)d_out, nullptr, ff2_b, 512, 512, 49408, 49408,
            0, 0, 0, 2432, 1.f);
}